// Round 8
// baseline (6401.024 us; speedup 1.0000x reference)
//
#include <hip/hip_runtime.h>

// ---------------- problem dims (fixed by reference) ----------------
#define T_   3
#define B_   16
#define D_   512
#define HW_  484
#define M_   1452          // T_*HW_
#define K_   128
#define TEMP_ 30.0f
#define EPS_  1e-5f
#define NORM_SCALE_ ((float)0.011048543456039806)

// ---------------- block-reduce helpers (blockDim == 256) ----------------
__device__ __forceinline__ float blockReduceSum256(float v) {
  __shared__ float red[4];
  #pragma unroll
  for (int o = 32; o > 0; o >>= 1) v += __shfl_xor(v, o);
  if ((threadIdx.x & 63) == 0) red[threadIdx.x >> 6] = v;
  __syncthreads();
  float t = red[0] + red[1] + red[2] + red[3];
  __syncthreads();
  return t;
}

__device__ __forceinline__ float blockReduceMax256(float v) {
  __shared__ float redm[4];
  #pragma unroll
  for (int o = 32; o > 0; o >>= 1) v = fmaxf(v, __shfl_xor(v, o));
  if ((threadIdx.x & 63) == 0) redm[threadIdx.x >> 6] = v;
  __syncthreads();
  float t = fmaxf(fmaxf(redm[0], redm[1]), fmaxf(redm[2], redm[3]));
  __syncthreads();
  return t;
}

// ---------------- softmax(qxm) -> wts[3] ----------------
__global__ void k_wts(const float* __restrict__ qxm, float* __restrict__ wts) {
  if (threadIdx.x == 0 && blockIdx.x == 0) {
    float a = qxm[0], b = qxm[1], c = qxm[2];
    float m = fmaxf(a, fmaxf(b, c));
    float ea = __expf(a - m), eb = __expf(b - m), ec = __expf(c - m);
    float s = ea + eb + ec;
    wts[0] = ea / s; wts[1] = eb / s; wts[2] = ec / s;
  }
}

// ---------------- zero a float buffer (n multiple of 4) ----------------
__global__ __launch_bounds__(256) void k_zero(float* __restrict__ p, long n4) {
  long i = (long)blockIdx.x*256 + threadIdx.x;
  if (i < n4) ((float4*)p)[i] = make_float4(0.f, 0.f, 0.f, 0.f);
}

// ---------------- feat [TB, D, HW] -> X [t*HW+hw, b, d] ----------------
__global__ __launch_bounds__(256) void k_transpose_in(
    const float* __restrict__ in, float* __restrict__ out) {
  __shared__ float tile[32][33];
  const int tb = blockIdx.z;           // t*B_+b
  const int t = tb / B_, b = tb % B_;
  const int hw0 = blockIdx.x * 32, d0 = blockIdx.y * 32;
  const int tx = threadIdx.x & 31, ty = threadIdx.x >> 5;   // 32x8
  for (int i = ty; i < 32; i += 8) {
    int d = d0 + i, hw = hw0 + tx;
    tile[i][tx] = (hw < HW_) ? in[((long)tb*D_ + d)*HW_ + hw] : 0.f;
  }
  __syncthreads();
  for (int i = ty; i < 32; i += 8) {
    int hw = hw0 + i, d = d0 + tx;
    if (hw < HW_) out[(((long)t*HW_ + hw)*B_ + b)*D_ + d] = tile[tx][i];
  }
}

// ---------------- outImg [hw,b,d] -> out [b, d, hw] (per image) ----------------
__global__ __launch_bounds__(256) void k_out_store(
    const float* __restrict__ Xo, float* __restrict__ outP) {
  __shared__ float tile[32][33];
  const int b = blockIdx.z;
  const int hw0 = blockIdx.x * 32, d0 = blockIdx.y * 32;
  const int tx = threadIdx.x & 31, ty = threadIdx.x >> 5;
  for (int i = ty; i < 32; i += 8) {
    int hw = hw0 + i, d = d0 + tx;
    tile[i][tx] = (hw < HW_) ? Xo[((long)hw*B_ + b)*D_ + d] : 0.f;
  }
  __syncthreads();
  for (int i = ty; i < 32; i += 8) {
    int d = d0 + i, hw = hw0 + tx;
    if (hw < HW_) outP[((long)b*D_ + d)*HW_ + hw] = tile[tx][i];
  }
}

// ---------------- Y[l,b,:] = l2norm(X[l,b,:] @ W^T + bias), K=128, D=512 ----------
__global__ __launch_bounds__(256) void k_proj_l2n(
    const float* __restrict__ X, const float* __restrict__ Wm,
    const float* __restrict__ bias, float* __restrict__ Y, int nRows) {
  __shared__ __align__(16) float sX[32][68];
  __shared__ __align__(16) float sW[128][68];
  const int tid = threadIdx.x;
  const int rp = tid >> 4;        // 0..15 row-pair
  const int kg = tid & 15;        // 0..15
  const int row0 = blockIdx.x * 32;
  float acc[2][8] = {};
  for (int dc = 0; dc < D_; dc += 64) {
    for (int f = tid; f < 32*16; f += 256) {
      int rr = f >> 4, c4 = (f & 15) * 4;
      int rg = row0 + rr;
      float4 v = make_float4(0.f, 0.f, 0.f, 0.f);
      if (rg < nRows) v = *(const float4*)&X[(long)rg*D_ + dc + c4];
      *(float4*)&sX[rr][c4] = v;
    }
    for (int f = tid; f < 128*16; f += 256) {
      int rr = f >> 4, c4 = (f & 15) * 4;
      *(float4*)&sW[rr][c4] = *(const float4*)&Wm[rr*D_ + dc + c4];
    }
    __syncthreads();
    #pragma unroll
    for (int d4 = 0; d4 < 64; d4 += 4) {
      float4 xa = *(const float4*)&sX[rp*2+0][d4];
      float4 xb = *(const float4*)&sX[rp*2+1][d4];
      #pragma unroll
      for (int i = 0; i < 8; i++) {
        float4 w = *(const float4*)&sW[kg + 16*i][d4];
        acc[0][i] += xa.x*w.x + xa.y*w.y + xa.z*w.z + xa.w*w.w;
        acc[1][i] += xb.x*w.x + xb.y*w.y + xb.z*w.z + xb.w*w.w;
      }
    }
    __syncthreads();
  }
  #pragma unroll
  for (int r = 0; r < 2; r++) {
    float ss = 0.f;
    #pragma unroll
    for (int i = 0; i < 8; i++) {
      acc[r][i] += bias[kg + 16*i];
      ss += acc[r][i] * acc[r][i];
    }
    ss += __shfl_xor(ss, 1); ss += __shfl_xor(ss, 2);
    ss += __shfl_xor(ss, 4); ss += __shfl_xor(ss, 8);
    float inv = 1.f / fmaxf(sqrtf(ss), 1e-12f);
    int rg = row0 + rp*2 + r;
    if (rg < nRows) {
      #pragma unroll
      for (int i = 0; i < 8; i++)
        Y[(long)rg*K_ + kg + 16*i] = acc[r][i] * inv;
    }
  }
}

// ------------- S[b,q,j] = TEMP * sum_e Q[q,b,e]*Kt[j,b,e] --------------------
template<int NJ>
__global__ __launch_bounds__(256) void k_scores(
    const float* __restrict__ Q, const float* __restrict__ Kt,
    float* __restrict__ S, int Lq, int Lk) {
  __shared__ __align__(16) float sQ[128][36];
  __shared__ __align__(16) float sK[NJ*16][36];
  const int b = blockIdx.z;
  const int q0 = blockIdx.x * 128;
  const int j0 = blockIdx.y * (NJ*16);
  const int tid = threadIdx.x;
  const int tx = tid & 15, ty = tid >> 4;
  float acc[8][NJ] = {};
  for (int ec = 0; ec < K_; ec += 32) {
    for (int f = tid; f < 128*8; f += 256) {
      int rr = f >> 3, c4 = (f & 7) * 4;
      int qg = q0 + rr;
      float4 v = make_float4(0.f, 0.f, 0.f, 0.f);
      if (qg < Lq) v = *(const float4*)&Q[((long)qg*B_ + b)*K_ + ec + c4];
      *(float4*)&sQ[rr][c4] = v;
    }
    for (int f = tid; f < NJ*16*8; f += 256) {
      int rr = f >> 3, c4 = (f & 7) * 4;
      int jg = j0 + rr;
      float4 v = make_float4(0.f, 0.f, 0.f, 0.f);
      if (jg < Lk) v = *(const float4*)&Kt[((long)jg*B_ + b)*K_ + ec + c4];
      *(float4*)&sK[rr][c4] = v;
    }
    __syncthreads();
    #pragma unroll
    for (int e4 = 0; e4 < 32; e4 += 4) {
      float4 qa[8]; float4 kb[NJ];
      #pragma unroll
      for (int i = 0; i < 8; i++) qa[i] = *(const float4*)&sQ[ty + 16*i][e4];
      #pragma unroll
      for (int j = 0; j < NJ; j++) kb[j] = *(const float4*)&sK[tx + 16*j][e4];
      #pragma unroll
      for (int i = 0; i < 8; i++)
        #pragma unroll
        for (int j = 0; j < NJ; j++)
          acc[i][j] += qa[i].x*kb[j].x + qa[i].y*kb[j].y
                     + qa[i].z*kb[j].z + qa[i].w*kb[j].w;
    }
    __syncthreads();
  }
  #pragma unroll
  for (int i = 0; i < 8; i++) {
    int qg = q0 + ty + 16*i;
    if (qg >= Lq) continue;
    float* row = S + ((long)b*Lq + qg)*Lk;
    #pragma unroll
    for (int j = 0; j < NJ; j++) {
      int jg = j0 + tx + 16*j;
      if (jg < Lk) row[jg] = TEMP_ * acc[i][j];
    }
  }
}

// ---------------- row softmax in place; len % 4 == 0, len <= 1452 ----------------
__global__ __launch_bounds__(256) void k_softmax(float* __restrict__ S, int len) {
  __shared__ __align__(16) float buf[1456];
  const long row = blockIdx.x;
  float* p = S + row * (long)len;
  const int tid = threadIdx.x;
  float mx = -1e30f;
  for (int i = tid*4; i < len; i += 1024) {
    float4 v = *(const float4*)&p[i];
    *(float4*)&buf[i] = v;
    mx = fmaxf(mx, fmaxf(fmaxf(v.x, v.y), fmaxf(v.z, v.w)));
  }
  mx = blockReduceMax256(mx);
  float sum = 0.f;
  for (int i = tid*4; i < len; i += 1024) {
    float4 v = *(float4*)&buf[i];
    v.x = __expf(v.x - mx); v.y = __expf(v.y - mx);
    v.z = __expf(v.z - mx); v.w = __expf(v.w - mx);
    sum += v.x + v.y + v.z + v.w;
    *(float4*)&buf[i] = v;
  }
  sum = blockReduceSum256(sum);
  float inv = 1.f / sum;
  for (int i = tid*4; i < len; i += 1024) {
    float4 v = *(float4*)&buf[i];
    v.x *= inv; v.y *= inv; v.z *= inv; v.w *= inv;
    *(float4*)&p[i] = v;
  }
}

// --------- dst[q,b,d0+..] (+)= sum_k S[b,q,k]*(pos1_k)*V[k,b,:] (+R) ----------
// Tile: 128(q) x 64*ND4(d). Thread: 8q x ND4 float4 (d = d0 + 4*tx + 64*jj).
// All inner LDS reads are b128. nParts>1: k-range split across blockIdx.z,
// ATOMIC accumulate into pre-zeroed dst (2 commutative adds -> deterministic).
template<int ND4, bool SCALE, bool ATOMIC>
__global__ __launch_bounds__(256) void k_av2(
    const float* __restrict__ S, const float* __restrict__ V,
    const float* __restrict__ R,              // residual (nullptr = none)
    const float* __restrict__ label,
    float* __restrict__ dst, int Lq, int Lk, int nParts) {
  __shared__ __align__(16) float sS[128][36];
  __shared__ __align__(16) float sV[32][64*ND4 + 4];
  const int part = blockIdx.z % nParts;
  const int b    = blockIdx.z / nParts;
  const int q0 = blockIdx.x * 128;
  const int d0 = blockIdx.y * (64*ND4);
  const int tid = threadIdx.x;
  const int tx = tid & 15, ty = tid >> 4;
  float4 acc[8][ND4];
  #pragma unroll
  for (int i = 0; i < 8; i++)
    #pragma unroll
    for (int jj = 0; jj < ND4; jj++)
      acc[i][jj] = make_float4(0.f, 0.f, 0.f, 0.f);

  const int chunksTotal = (Lk + 31) / 32;
  const int perPart = (chunksTotal + nParts - 1) / nParts;
  const int c0 = part * perPart;
  const int c1 = (c0 + perPart < chunksTotal) ? (c0 + perPart) : chunksTotal;

  for (int c = c0; c < c1; ++c) {
    const int k0 = c * 32;
    // stage S tile [128 q][32 k] (optionally pre-scaled by pos1)
    for (int f = tid; f < 128*8; f += 256) {
      int rr = f >> 3, c4 = (f & 7) * 4;
      int qg = q0 + rr, kk = k0 + c4;
      float4 v = make_float4(0.f, 0.f, 0.f, 0.f);
      if (qg < Lq && kk < Lk) v = *(const float4*)&S[((long)b*Lq + qg)*Lk + kk];
      if (SCALE) {
        float* pv = (float*)&v;
        #pragma unroll
        for (int u = 0; u < 4; u++) {
          int kj = kk + u;
          float pl = 0.f;
          if (kj < Lk) {
            int pp = kj / HW_, hh = kj - pp*HW_;
            pl = label[(pp*B_ + b)*HW_ + hh];
          }
          pv[u] *= pl;
        }
      }
      *(float4*)&sS[rr][c4] = v;
    }
    // stage V tile [32 k][64*ND4 d]
    for (int f = tid; f < 32*ND4*16; f += 256) {
      int kk = f / (ND4*16), c4 = (f % (ND4*16)) * 4;
      int kg = k0 + kk;
      float4 v = make_float4(0.f, 0.f, 0.f, 0.f);
      if (kg < Lk) v = *(const float4*)&V[((long)kg*B_ + b)*D_ + d0 + c4];
      *(float4*)&sV[kk][c4] = v;
    }
    __syncthreads();
    #pragma unroll
    for (int k4 = 0; k4 < 32; k4 += 4) {
      float4 qa[8];
      #pragma unroll
      for (int i = 0; i < 8; i++) qa[i] = *(const float4*)&sS[ty + 16*i][k4];
      #pragma unroll
      for (int u = 0; u < 4; u++) {
        float4 vb[ND4];
        #pragma unroll
        for (int jj = 0; jj < ND4; jj++)
          vb[jj] = *(const float4*)&sV[k4 + u][4*tx + 64*jj];
        #pragma unroll
        for (int i = 0; i < 8; i++) {
          float qv = (u == 0) ? qa[i].x : (u == 1) ? qa[i].y
                   : (u == 2) ? qa[i].z : qa[i].w;
          #pragma unroll
          for (int jj = 0; jj < ND4; jj++) {
            acc[i][jj].x += qv * vb[jj].x;
            acc[i][jj].y += qv * vb[jj].y;
            acc[i][jj].z += qv * vb[jj].z;
            acc[i][jj].w += qv * vb[jj].w;
          }
        }
      }
    }
    __syncthreads();
  }
  // epilogue
  #pragma unroll
  for (int i = 0; i < 8; i++) {
    int qg = q0 + ty + 16*i;
    if (qg >= Lq) continue;
    long off = ((long)qg*B_ + b)*D_ + d0 + 4*tx;
    #pragma unroll
    for (int jj = 0; jj < ND4; jj++) {
      float4 o = acc[i][jj];
      if (ATOMIC) {
        float* p = dst + off + 64*jj;
        atomicAdd(p+0, o.x); atomicAdd(p+1, o.y);
        atomicAdd(p+2, o.z); atomicAdd(p+3, o.w);
      } else {
        if (R) {
          float4 r = *(const float4*)&R[off + 64*jj];
          o.x += r.x; o.y += r.y; o.z += r.z; o.w += r.w;
        }
        *(float4*)&dst[off + 64*jj] = o;
      }
    }
  }
}

// ------- fused: W2[b,q,k] = sum_p SC[b,q,p*HW+k]*label[p,b,k]; mask = row-sum ----
__global__ __launch_bounds__(256) void k_w2m(
    const float* __restrict__ SC, const float* __restrict__ label,
    float* __restrict__ W2, float* __restrict__ maskB) {
  const int row = blockIdx.x;            // b*HW_+q
  const int b = row / HW_;
  const int q = row - b*HW_;
  const float* srow = SC + (long)row * M_;
  float s = 0.f;
  for (int k = threadIdx.x; k < HW_; k += 256) {
    float w = srow[k]         * label[(0*B_ + b)*HW_ + k]
            + srow[HW_ + k]   * label[(1*B_ + b)*HW_ + k]
            + srow[2*HW_ + k] * label[(2*B_ + b)*HW_ + k];
    W2[(long)row*HW_ + k] = w;
    s += w;
  }
  s = blockReduceSum256(s);
  if (threadIdx.x == 0) maskB[q*B_ + b] = s;
}

// ------- inorm pass 1: partial sums of squares per (g,b), 16 chunks -------
// X2 (nullable): elementwise added to X before squaring (split-K residual fold)
template<bool WM>
__global__ __launch_bounds__(256) void k_ss_partial(
    const float* __restrict__ X, const float* __restrict__ X2,
    const float* __restrict__ maskB, float* __restrict__ part) {
  const int gb = blockIdx.x;           // g*B_+b
  const int c = blockIdx.y;            // 0..15
  const int g = gb / B_, b = gb % B_;
  const float4* Xp = (const float4*)X;
  const float4* X2p = (const float4*)X2;
  const int CH = (HW_*D_/4) / 16;
  float s = 0.f;
  for (int i = c*CH + threadIdx.x; i < (c+1)*CH; i += 256) {
    int hw = i >> 7;
    int d4 = i & 127;
    long idx = (((long)g*HW_ + hw)*B_ + b)*(D_/4) + d4;
    float4 v = Xp[idx];
    if (X2p) {
      float4 v2 = X2p[idx];
      v.x += v2.x; v.y += v2.y; v.z += v2.z; v.w += v2.w;
    }
    float m = 1.f;
    if (WM) m = maskB[hw*B_ + b];
    float a = v.x*m, e = v.y*m, f = v.z*m, h = v.w*m;
    s += a*a + e*e + f*f + h*h;
  }
  s = blockReduceSum256(s);
  if (threadIdx.x == 0) part[gb*16 + c] = s;
}

// ------- inorm pass 2: scale factor per group -------
__global__ void k_ss_final(const float* __restrict__ part,
                           float* __restrict__ scaleG, int nG) {
  int g = threadIdx.x;
  if (g < nG) {
    float s = 0.f;
    #pragma unroll
    for (int c = 0; c < 16; c++) s += part[g*16 + c];
    scaleG[g] = NORM_SCALE_ * sqrtf((float)(D_*HW_) / (s + EPS_));
  }
}

// ------- x *= scaleG[g*B+b], x is [G*HW, B, D] viewed as float4 -------
__global__ __launch_bounds__(256) void k_inorm_apply(
    float* __restrict__ X, const float* __restrict__ scaleG, long n4) {
  long i = (long)blockIdx.x*256 + threadIdx.x;
  if (i >= n4) return;
  long t = i >> 7;
  int b = (int)(t & 15);
  long l = t >> 4;
  int g = (int)(l / HW_);
  float sc = scaleG[g*B_ + b];
  float4* Xp = (float4*)X;
  float4 v = Xp[i];
  v.x *= sc; v.y *= sc; v.z *= sc; v.w *= sc;
  Xp[i] = v;
}

// ------- outImg (+)= wts[widx]*scale[b]*((X (+X2)) or tgt*mask) -------
template<int MODE>   // 0: overwrite with tgt*mask ; 1: add (X + X2)
__global__ __launch_bounds__(256) void k_accum(
    const float* __restrict__ X, const float* __restrict__ X2,
    const float* __restrict__ maskB, const float* __restrict__ scaleG,
    const float* __restrict__ wts, float* __restrict__ outI, int widx) {
  long i = (long)blockIdx.x*256 + threadIdx.x;
  const long n4 = (long)HW_*B_*D_/4;
  if (i >= n4) return;
  long t = i >> 7;
  int b = (int)(t & 15);
  int hw = (int)(t >> 4);
  float w = wts[widx] * scaleG[b];
  if (MODE == 0) w *= maskB[hw*B_ + b];
  float4 v = ((const float4*)X)[i];
  if (MODE == 1 && X2) {
    float4 v2 = ((const float4*)X2)[i];
    v.x += v2.x; v.y += v2.y; v.z += v2.z; v.w += v2.w;
  }
  float4* Op = (float4*)outI;
  if (MODE == 0) {
    Op[i] = make_float4(v.x*w, v.y*w, v.z*w, v.w*w);
  } else {
    float4 o = Op[i];
    o.x += v.x*w; o.y += v.y*w; o.z += v.z*w; o.w += v.w*w;
    Op[i] = o;
  }
}

// =======================================================================
extern "C" void kernel_launch(void* const* d_in, const int* in_sizes, int n_in,
                              void* d_out, int out_size, void* d_ws, size_t ws_size,
                              hipStream_t stream) {
  (void)in_sizes; (void)n_in; (void)out_size; (void)ws_size;
  const float* train_feat = (const float*)d_in[0];
  const float* test_feat  = (const float*)d_in[1];
  const float* label      = (const float*)d_in[2];
  const float* sw  = (const float*)d_in[3];
  const float* sb  = (const float*)d_in[4];
  const float* cw  = (const float*)d_in[5];
  const float* cb  = (const float*)d_in[6];
  const float* qxm = (const float*)d_in[7];
  float* out = (float*)d_out;

  // ---- workspace layout (floats) ----
  float* ws = (float*)d_ws;
  long o = 0;
  float* srcT  = ws + o; o += (long)M_*B_*D_;
  float* tstT  = ws + o; o += (long)M_*B_*D_;
  float* mem   = ws + o; o += (long)M_*B_*D_;
  float* wkMem = ws + o; o += (long)M_*B_*K_;
  float* wq    = ws + o; o += (long)M_*B_*K_;
  float* big   = ws + o; o += (long)B_*M_*M_;
  float* maskB = ws + o; o += HW_*B_;
  float* part  = ws + o; o += T_*B_*16;
  float* scaleG= ws + o; o += 64;
  float* wts   = ws + o; o += 4;

  // decoder sub-buffers inside `big`
  float* scoresC = big;                               // [B,HW,M]
  float* scoresS = scoresC + (long)B_*HW_*M_;         // [B,HW,HW]
  float* W2      = scoresS + (long)B_*HW_*HW_;        // [B,HW,HW]
  float* tgt     = W2      + (long)B_*HW_*HW_;        // [HW,B,D]
  float* Xbuf    = tgt     + (long)HW_*B_*D_;         // [HW,B,D]
  float* outImg  = Xbuf    + (long)HW_*B_*D_;         // [HW,B,D]

  const long imgN4 = (long)HW_*B_*D_/4;
  const int  imgBlocks = (int)((imgN4 + 255)/256);

  // ---- input transposes + qxm softmax ----
  k_transpose_in<<<dim3(16,16,T_*B_),256,0,stream>>>(train_feat, srcT);
  k_transpose_in<<<dim3(16,16,T_*B_),256,0,stream>>>(test_feat,  tstT);
  k_wts<<<1,64,0,stream>>>(qxm, wts);

  // ---- encoder: memory = inorm(src + selfattn(src), T) ----
  k_proj_l2n<<<(M_*B_+31)/32,256,0,stream>>>(srcT, sw, sb, wq, M_*B_);
  k_scores<8><<<dim3((M_+127)/128,(M_+127)/128,B_),256,0,stream>>>(wq, wq, big, M_, M_);
  k_softmax<<<B_*M_,256,0,stream>>>(big, M_);
  k_av2<2,false,false><<<dim3((M_+127)/128, D_/128, B_),256,0,stream>>>(
      big, srcT, srcT, nullptr, mem, M_, M_, 1);
  k_ss_partial<false><<<dim3(T_*B_,16),256,0,stream>>>(mem, nullptr, nullptr, part);
  k_ss_final<<<1,64,0,stream>>>(part, scaleG, T_*B_);
  k_inorm_apply<<<(int)(((long)M_*B_*D_/4 + 255)/256),256,0,stream>>>(
      mem, scaleG, (long)M_*B_*D_/4);
  k_proj_l2n<<<(M_*B_+31)/32,256,0,stream>>>(mem, cw, cb, wkMem, M_*B_);

  // ---- decoder: 3 train images then 3 test images ----
  for (int img = 0; img < 2*T_; img++) {
    const float* base = (img < T_) ? srcT + (long)img*HW_*B_*D_
                                   : tstT + (long)(img - T_)*HW_*B_*D_;
    float* outP = out + (long)img*B_*D_*HW_;

    // self-attention + inorm -> tgt
    k_proj_l2n<<<(HW_*B_+31)/32,256,0,stream>>>(base, sw, sb, wq, HW_*B_);
    k_scores<4><<<dim3((HW_+127)/128,(HW_+63)/64,B_),256,0,stream>>>(
        wq, wq, scoresS, HW_, HW_);
    k_softmax<<<B_*HW_,256,0,stream>>>(scoresS, HW_);
    k_av2<1,false,false><<<dim3((HW_+127)/128, D_/64, B_),256,0,stream>>>(
        scoresS, base, base, nullptr, tgt, HW_, HW_, 1);
    k_ss_partial<false><<<dim3(B_,16),256,0,stream>>>(tgt, nullptr, nullptr, part);
    k_ss_final<<<1,64,0,stream>>>(part, scaleG, B_);
    k_inorm_apply<<<imgBlocks,256,0,stream>>>(tgt, scaleG, imgN4);

    // shared cross-attention weights aff = softmax(30*wq(tgt)·wk(memory))
    k_proj_l2n<<<(HW_*B_+31)/32,256,0,stream>>>(tgt, cw, cb, wq, HW_*B_);
    k_scores<8><<<dim3((HW_+127)/128,(M_+127)/128,B_),256,0,stream>>>(
        wq, wkMem, scoresC, HW_, M_);
    k_softmax<<<B_*HW_,256,0,stream>>>(scoresC, M_);

    // W2 + mask (fused)
    k_w2m<<<B_*HW_,256,0,stream>>>(scoresC, label, W2, maskB);

    // t_base = inorm(tgt*mask):  out = w0*scale*tgt*mask
    k_ss_partial<true><<<dim3(B_,16),256,0,stream>>>(tgt, nullptr, maskB, part);
    k_ss_final<<<1,64,0,stream>>>(part, scaleG, B_);
    k_accum<0><<<imgBlocks,256,0,stream>>>(
        tgt, nullptr, maskB, scaleG, wts, outImg, 0);

    // t_q = inorm(W2@tgt + tgt):  out += w1*scale*X
    k_av2<1,false,false><<<dim3((HW_+127)/128, D_/64, B_),256,0,stream>>>(
        W2, tgt, tgt, nullptr, Xbuf, HW_, HW_, 1);
    k_ss_partial<false><<<dim3(B_,16),256,0,stream>>>(Xbuf, nullptr, nullptr, part);
    k_ss_final<<<1,64,0,stream>>>(part, scaleG, B_);
    k_accum<1><<<imgBlocks,256,0,stream>>>(
        Xbuf, nullptr, nullptr, scaleG, wts, outImg, 1);

    // t_v = inorm((aff*pos1)@memory + tgt):  out += w2*scale*(Xbuf+tgt)
    // split-K=2 with deterministic atomic accumulation into zeroed Xbuf
    k_zero<<<(int)((imgN4 + 255)/256),256,0,stream>>>(Xbuf, imgN4);
    k_av2<2,true,true><<<dim3((HW_+127)/128, D_/128, B_*2),256,0,stream>>>(
        scoresC, mem, nullptr, label, Xbuf, HW_, M_, 2);
    k_ss_partial<false><<<dim3(B_,16),256,0,stream>>>(Xbuf, tgt, nullptr, part);
    k_ss_final<<<1,64,0,stream>>>(part, scaleG, B_);
    k_accum<1><<<imgBlocks,256,0,stream>>>(
        Xbuf, tgt, nullptr, scaleG, wts, outImg, 2);

    k_out_store<<<dim3(16,16,B_),256,0,stream>>>(outImg, outP);
  }
}

// Round 10
// 5057.905 us; speedup vs baseline: 1.2655x; 1.2655x over previous
//
#include <hip/hip_runtime.h>

// ---------------- problem dims (fixed by reference) ----------------
#define T_   3
#define B_   16
#define D_   512
#define HW_  484
#define M_   1452          // T_*HW_
#define K_   128
#define TEMP_ 30.0f
#define EPS_  1e-5f
#define NORM_SCALE_ ((float)0.011048543456039806)
#define MP_M  1472         // M padded to multiple of 32 (bf16 VT buffers)
#define MP_HW 512          // HW padded to multiple of 32

typedef __attribute__((ext_vector_type(8))) short short8v;   // 8 bf16 (4 VGPRs)
typedef __attribute__((ext_vector_type(4))) float floatx4;   // MFMA C/D

// fp32 -> bf16 round-to-nearest-even
__device__ __forceinline__ unsigned short f2bf(float x) {
  unsigned int u = __float_as_uint(x);
  u += 0x7fffu + ((u >> 16) & 1u);
  return (unsigned short)(u >> 16);
}

// ---------------- block-reduce helpers (blockDim == 256) ----------------
__device__ __forceinline__ float blockReduceSum256(float v) {
  __shared__ float red[4];
  #pragma unroll
  for (int o = 32; o > 0; o >>= 1) v += __shfl_xor(v, o);
  if ((threadIdx.x & 63) == 0) red[threadIdx.x >> 6] = v;
  __syncthreads();
  float t = red[0] + red[1] + red[2] + red[3];
  __syncthreads();
  return t;
}

__device__ __forceinline__ float blockReduceMax256(float v) {
  __shared__ float redm[4];
  #pragma unroll
  for (int o = 32; o > 0; o >>= 1) v = fmaxf(v, __shfl_xor(v, o));
  if ((threadIdx.x & 63) == 0) redm[threadIdx.x >> 6] = v;
  __syncthreads();
  float t = fmaxf(fmaxf(redm[0], redm[1]), fmaxf(redm[2], redm[3]));
  __syncthreads();
  return t;
}

// ---------------- softmax(qxm) -> wts[3] ----------------
__global__ void k_wts(const float* __restrict__ qxm, float* __restrict__ wts) {
  if (threadIdx.x == 0 && blockIdx.x == 0) {
    float a = qxm[0], b = qxm[1], c = qxm[2];
    float m = fmaxf(a, fmaxf(b, c));
    float ea = __expf(a - m), eb = __expf(b - m), ec = __expf(c - m);
    float s = ea + eb + ec;
    wts[0] = ea / s; wts[1] = eb / s; wts[2] = ec / s;
  }
}

// ---------------- feat [TB, D, HW] -> X [t*HW+hw, b, d] ----------------
__global__ __launch_bounds__(256) void k_transpose_in(
    const float* __restrict__ in, float* __restrict__ out) {
  __shared__ float tile[32][33];
  const int tb = blockIdx.z;           // t*B_+b
  const int t = tb / B_, b = tb % B_;
  const int hw0 = blockIdx.x * 32, d0 = blockIdx.y * 32;
  const int tx = threadIdx.x & 31, ty = threadIdx.x >> 5;   // 32x8
  for (int i = ty; i < 32; i += 8) {
    int d = d0 + i, hw = hw0 + tx;
    tile[i][tx] = (hw < HW_) ? in[((long)tb*D_ + d)*HW_ + hw] : 0.f;
  }
  __syncthreads();
  for (int i = ty; i < 32; i += 8) {
    int hw = hw0 + i, d = d0 + tx;
    if (hw < HW_) out[(((long)t*HW_ + hw)*B_ + b)*D_ + d] = tile[tx][i];
  }
}

// ---------------- outImg [hw,b,d] -> out [b, d, hw] (per image) ----------------
__global__ __launch_bounds__(256) void k_out_store(
    const float* __restrict__ Xo, float* __restrict__ outP) {
  __shared__ float tile[32][33];
  const int b = blockIdx.z;
  const int hw0 = blockIdx.x * 32, d0 = blockIdx.y * 32;
  const int tx = threadIdx.x & 31, ty = threadIdx.x >> 5;
  for (int i = ty; i < 32; i += 8) {
    int hw = hw0 + i, d = d0 + tx;
    tile[i][tx] = (hw < HW_) ? Xo[((long)hw*B_ + b)*D_ + d] : 0.f;
  }
  __syncthreads();
  for (int i = ty; i < 32; i += 8) {
    int d = d0 + i, hw = hw0 + tx;
    if (hw < HW_) outP[((long)b*D_ + d)*HW_ + hw] = tile[tx][i];
  }
}

// ----- X [L, B, D] fp32 -> XT [B][D][Mp] bf16 (zero-padded l in [L,Mp)) -----
__global__ __launch_bounds__(256) void k_cvtT(
    const float* __restrict__ X, unsigned short* __restrict__ XT,
    int L, int Mp) {
  __shared__ float tile[32][33];     // [d-idx][l-idx]
  const int b = blockIdx.z;
  const int l0 = blockIdx.x * 32, d0 = blockIdx.y * 32;
  const int tx = threadIdx.x & 31, ty = threadIdx.x >> 5;
  for (int i = ty; i < 32; i += 8) {
    int l = l0 + i;
    float v = 0.f;
    if (l < L) v = X[((long)l*B_ + b)*D_ + d0 + tx];   // coalesced in d
    tile[tx][i] = v;
  }
  __syncthreads();
  const int di = threadIdx.x >> 3, quad = threadIdx.x & 7;  // 4 l per thread
  ushort4 w;
  w.x = f2bf(tile[di][4*quad+0]);
  w.y = f2bf(tile[di][4*quad+1]);
  w.z = f2bf(tile[di][4*quad+2]);
  w.w = f2bf(tile[di][4*quad+3]);
  *(ushort4*)&XT[((long)b*D_ + d0 + di)*Mp + l0 + 4*quad] = w;
}

// ---------------- Y[l,b,:] = l2norm(X[l,b,:] @ W^T + bias), K=128, D=512 ----------
__global__ __launch_bounds__(256) void k_proj_l2n(
    const float* __restrict__ X, const float* __restrict__ Wm,
    const float* __restrict__ bias, float* __restrict__ Y, int nRows) {
  __shared__ __align__(16) float sX[32][68];
  __shared__ __align__(16) float sW[128][68];
  const int tid = threadIdx.x;
  const int rp = tid >> 4;        // 0..15 row-pair
  const int kg = tid & 15;        // 0..15
  const int row0 = blockIdx.x * 32;
  float acc[2][8] = {};
  for (int dc = 0; dc < D_; dc += 64) {
    for (int f = tid; f < 32*16; f += 256) {
      int rr = f >> 4, c4 = (f & 15) * 4;
      int rg = row0 + rr;
      float4 v = make_float4(0.f, 0.f, 0.f, 0.f);
      if (rg < nRows) v = *(const float4*)&X[(long)rg*D_ + dc + c4];
      *(float4*)&sX[rr][c4] = v;
    }
    for (int f = tid; f < 128*16; f += 256) {
      int rr = f >> 4, c4 = (f & 15) * 4;
      *(float4*)&sW[rr][c4] = *(const float4*)&Wm[rr*D_ + dc + c4];
    }
    __syncthreads();
    #pragma unroll
    for (int d4 = 0; d4 < 64; d4 += 4) {
      float4 xa = *(const float4*)&sX[rp*2+0][d4];
      float4 xb = *(const float4*)&sX[rp*2+1][d4];
      #pragma unroll
      for (int i = 0; i < 8; i++) {
        float4 w = *(const float4*)&sW[kg + 16*i][d4];
        acc[0][i] += xa.x*w.x + xa.y*w.y + xa.z*w.z + xa.w*w.w;
        acc[1][i] += xb.x*w.x + xb.y*w.y + xb.z*w.z + xb.w*w.w;
      }
    }
    __syncthreads();
  }
  #pragma unroll
  for (int r = 0; r < 2; r++) {
    float ss = 0.f;
    #pragma unroll
    for (int i = 0; i < 8; i++) {
      acc[r][i] += bias[kg + 16*i];
      ss += acc[r][i] * acc[r][i];
    }
    ss += __shfl_xor(ss, 1); ss += __shfl_xor(ss, 2);
    ss += __shfl_xor(ss, 4); ss += __shfl_xor(ss, 8);
    float inv = 1.f / fmaxf(sqrtf(ss), 1e-12f);
    int rg = row0 + rp*2 + r;
    if (rg < nRows) {
      #pragma unroll
      for (int i = 0; i < 8; i++)
        Y[(long)rg*K_ + kg + 16*i] = acc[r][i] * inv;
    }
  }
}

// ------------- S[b,q,j] = TEMP * sum_e Q[q,b,e]*Kt[j,b,e] --------------------
template<int NJ>
__global__ __launch_bounds__(256) void k_scores(
    const float* __restrict__ Q, const float* __restrict__ Kt,
    float* __restrict__ S, int Lq, int Lk) {
  __shared__ __align__(16) float sQ[128][36];
  __shared__ __align__(16) float sK[NJ*16][36];
  const int b = blockIdx.z;
  const int q0 = blockIdx.x * 128;
  const int j0 = blockIdx.y * (NJ*16);
  const int tid = threadIdx.x;
  const int tx = tid & 15, ty = tid >> 4;
  float acc[8][NJ] = {};
  for (int ec = 0; ec < K_; ec += 32) {
    for (int f = tid; f < 128*8; f += 256) {
      int rr = f >> 3, c4 = (f & 7) * 4;
      int qg = q0 + rr;
      float4 v = make_float4(0.f, 0.f, 0.f, 0.f);
      if (qg < Lq) v = *(const float4*)&Q[((long)qg*B_ + b)*K_ + ec + c4];
      *(float4*)&sQ[rr][c4] = v;
    }
    for (int f = tid; f < NJ*16*8; f += 256) {
      int rr = f >> 3, c4 = (f & 7) * 4;
      int jg = j0 + rr;
      float4 v = make_float4(0.f, 0.f, 0.f, 0.f);
      if (jg < Lk) v = *(const float4*)&Kt[((long)jg*B_ + b)*K_ + ec + c4];
      *(float4*)&sK[rr][c4] = v;
    }
    __syncthreads();
    #pragma unroll
    for (int e4 = 0; e4 < 32; e4 += 4) {
      float4 qa[8]; float4 kb[NJ];
      #pragma unroll
      for (int i = 0; i < 8; i++) qa[i] = *(const float4*)&sQ[ty + 16*i][e4];
      #pragma unroll
      for (int j = 0; j < NJ; j++) kb[j] = *(const float4*)&sK[tx + 16*j][e4];
      #pragma unroll
      for (int i = 0; i < 8; i++)
        #pragma unroll
        for (int j = 0; j < NJ; j++)
          acc[i][j] += qa[i].x*kb[j].x + qa[i].y*kb[j].y
                     + qa[i].z*kb[j].z + qa[i].w*kb[j].w;
    }
    __syncthreads();
  }
  #pragma unroll
  for (int i = 0; i < 8; i++) {
    int qg = q0 + ty + 16*i;
    if (qg >= Lq) continue;
    float* row = S + ((long)b*Lq + qg)*Lk;
    #pragma unroll
    for (int j = 0; j < NJ; j++) {
      int jg = j0 + tx + 16*j;
      if (jg < Lk) row[jg] = TEMP_ * acc[i][j];
    }
  }
}

// ---------------- row softmax in place; len % 4 == 0, len <= 1452 ----------------
__global__ __launch_bounds__(256) void k_softmax(float* __restrict__ S, int len) {
  __shared__ __align__(16) float buf[1456];
  const long row = blockIdx.x;
  float* p = S + row * (long)len;
  const int tid = threadIdx.x;
  float mx = -1e30f;
  for (int i = tid*4; i < len; i += 1024) {
    float4 v = *(const float4*)&p[i];
    *(float4*)&buf[i] = v;
    mx = fmaxf(mx, fmaxf(fmaxf(v.x, v.y), fmaxf(v.z, v.w)));
  }
  mx = blockReduceMax256(mx);
  float sum = 0.f;
  for (int i = tid*4; i < len; i += 1024) {
    float4 v = *(float4*)&buf[i];
    v.x = __expf(v.x - mx); v.y = __expf(v.y - mx);
    v.z = __expf(v.z - mx); v.w = __expf(v.w - mx);
    sum += v.x + v.y + v.z + v.w;
    *(float4*)&buf[i] = v;
  }
  sum = blockReduceSum256(sum);
  float inv = 1.f / sum;
  for (int i = tid*4; i < len; i += 1024) {
    float4 v = *(float4*)&buf[i];
    v.x *= inv; v.y *= inv; v.z *= inv; v.w *= inv;
    *(float4*)&p[i] = v;
  }
}

// ========== MFMA AV: dst[q,b,d] = sum_k S[b,q,k]*(pos1_k)*V[k,b,d] (+R) ==========
// S fp32 (converted to bf16 while staging), VT bf16 [b][d][Mp] (k-contiguous).
// Block: 128q x 64d, 4 waves (wave w: q rows 32w..32w+32).
// MFMA 16x16x32 bf16; C/D layout col=lane&15, row=(lane>>4)*4+reg [m89-verified].
template<bool SCALE>
__global__ __launch_bounds__(256) void k_av_mfma(
    const float* __restrict__ S, const unsigned short* __restrict__ VT,
    const float* __restrict__ R, const float* __restrict__ label,
    float* __restrict__ dst, int Lq, int Lk, int Mp) {
  __shared__ __align__(16) unsigned short sS[128][40];   // 32 bf16 + pad (80 B rows)
  __shared__ __align__(16) unsigned short sV[64][40];
  const int b = blockIdx.z;
  const int q0 = blockIdx.x * 128, d0 = blockIdx.y * 64;
  const int tid = threadIdx.x;
  const int wid = tid >> 6, lane = tid & 63;
  floatx4 acc[2][4];
  #pragma unroll
  for (int i = 0; i < 2; i++)
    #pragma unroll
    for (int j = 0; j < 4; j++)
      acc[i][j] = (floatx4){0.f, 0.f, 0.f, 0.f};

  const int srr = tid >> 1, shalf = tid & 1;   // S stage: row, 16-col half
  const int vdr = tid >> 2, vq = tid & 3;      // V stage: row, 16B quarter
  const int nch = (Lk + 31) / 32;

  for (int c = 0; c < nch; ++c) {
    const int k0 = c * 32;
    // --- stage S tile [128 q][32 k] fp32 -> bf16 (optional pos1 scale) ---
    {
      int qg = q0 + srr;
      unsigned short outv[16];
      #pragma unroll
      for (int u = 0; u < 4; ++u) {
        int kk = k0 + 16*shalf + 4*u;
        float4 v = make_float4(0.f, 0.f, 0.f, 0.f);
        if (qg < Lq && kk < Lk) v = *(const float4*)&S[((long)b*Lq + qg)*Lk + kk];
        if (SCALE) {
          float* pv = (float*)&v;
          #pragma unroll
          for (int e = 0; e < 4; ++e) {
            int kj = kk + e;
            if (kj < Lk) {
              int pp = kj / HW_, hh = kj - pp*HW_;
              pv[e] *= label[(pp*B_ + b)*HW_ + hh];
            }
          }
        }
        outv[4*u+0] = f2bf(v.x); outv[4*u+1] = f2bf(v.y);
        outv[4*u+2] = f2bf(v.z); outv[4*u+3] = f2bf(v.w);
      }
      *(uint4*)&sS[srr][16*shalf]     = *(uint4*)&outv[0];
      *(uint4*)&sS[srr][16*shalf + 8] = *(uint4*)&outv[8];
    }
    // --- stage V tile [64 d][32 k] bf16 from global VT (k-padded, in-bounds) ---
    {
      uint4 v = *(const uint4*)&VT[((long)b*D_ + d0 + vdr)*Mp + k0 + 8*vq];
      *(uint4*)&sV[vdr][8*vq] = v;
    }
    __syncthreads();
    // --- MFMA: wave w covers q rows 32w..32w+32, all 64 d ---
    {
      const int arow = lane & 15;
      const int kof = (lane >> 4) * 8;
      short8v a0 = *(const short8v*)&sS[32*wid + arow][kof];
      short8v a1 = *(const short8v*)&sS[32*wid + 16 + arow][kof];
      #pragma unroll
      for (int td = 0; td < 4; ++td) {
        short8v bf = *(const short8v*)&sV[16*td + arow][kof];
        acc[0][td] = __builtin_amdgcn_mfma_f32_16x16x32_bf16(a0, bf, acc[0][td], 0, 0, 0);
        acc[1][td] = __builtin_amdgcn_mfma_f32_16x16x32_bf16(a1, bf, acc[1][td], 0, 0, 0);
      }
    }
    __syncthreads();
  }
  // --- epilogue: D[row][col], row=(lane>>4)*4+r, col=lane&15 ---
  const int col = lane & 15, row4 = (lane >> 4) * 4;
  #pragma unroll
  for (int tq = 0; tq < 2; ++tq) {
    #pragma unroll
    for (int r = 0; r < 4; ++r) {
      int q = q0 + 32*wid + 16*tq + row4 + r;
      if (q >= Lq) continue;
      long base = ((long)q*B_ + b)*D_ + d0 + col;
      #pragma unroll
      for (int td = 0; td < 4; ++td) {
        float v = acc[tq][td][r];
        long idx = base + 16*td;
        if (R) v += R[idx];
        dst[idx] = v;
      }
    }
  }
}

// ------- fused: W2[b,q,k] = sum_p SC[b,q,p*HW+k]*label[p,b,k]; mask = row-sum ----
__global__ __launch_bounds__(256) void k_w2m(
    const float* __restrict__ SC, const float* __restrict__ label,
    float* __restrict__ W2, float* __restrict__ maskB) {
  const int row = blockIdx.x;            // b*HW_+q
  const int b = row / HW_;
  const int q = row - b*HW_;
  const float* srow = SC + (long)row * M_;
  float s = 0.f;
  for (int k = threadIdx.x; k < HW_; k += 256) {
    float w = srow[k]         * label[(0*B_ + b)*HW_ + k]
            + srow[HW_ + k]   * label[(1*B_ + b)*HW_ + k]
            + srow[2*HW_ + k] * label[(2*B_ + b)*HW_ + k];
    W2[(long)row*HW_ + k] = w;
    s += w;
  }
  s = blockReduceSum256(s);
  if (threadIdx.x == 0) maskB[q*B_ + b] = s;
}

// ------- inorm pass 1: partial sums of squares per (g,b), 16 chunks -------
template<bool WM>
__global__ __launch_bounds__(256) void k_ss_partial(
    const float* __restrict__ X, const float* __restrict__ X2,
    const float* __restrict__ maskB, float* __restrict__ part) {
  const int gb = blockIdx.x;           // g*B_+b
  const int c = blockIdx.y;            // 0..15
  const int g = gb / B_, b = gb % B_;
  const float4* Xp = (const float4*)X;
  const float4* X2p = (const float4*)X2;
  const int CH = (HW_*D_/4) / 16;
  float s = 0.f;
  for (int i = c*CH + threadIdx.x; i < (c+1)*CH; i += 256) {
    int hw = i >> 7;
    int d4 = i & 127;
    long idx = (((long)g*HW_ + hw)*B_ + b)*(D_/4) + d4;
    float4 v = Xp[idx];
    if (X2p) {
      float4 v2 = X2p[idx];
      v.x += v2.x; v.y += v2.y; v.z += v2.z; v.w += v2.w;
    }
    float m = 1.f;
    if (WM) m = maskB[hw*B_ + b];
    float a = v.x*m, e = v.y*m, f = v.z*m, h = v.w*m;
    s += a*a + e*e + f*f + h*h;
  }
  s = blockReduceSum256(s);
  if (threadIdx.x == 0) part[gb*16 + c] = s;
}

// ------- inorm pass 2: scale factor per group -------
__global__ void k_ss_final(const float* __restrict__ part,
                           float* __restrict__ scaleG, int nG) {
  int g = threadIdx.x;
  if (g < nG) {
    float s = 0.f;
    #pragma unroll
    for (int c = 0; c < 16; c++) s += part[g*16 + c];
    scaleG[g] = NORM_SCALE_ * sqrtf((float)(D_*HW_) / (s + EPS_));
  }
}

// ------- x *= scaleG[g*B+b], x is [G*HW, B, D] viewed as float4 -------
__global__ __launch_bounds__(256) void k_inorm_apply(
    float* __restrict__ X, const float* __restrict__ scaleG, long n4) {
  long i = (long)blockIdx.x*256 + threadIdx.x;
  if (i >= n4) return;
  long t = i >> 7;
  int b = (int)(t & 15);
  long l = t >> 4;
  int g = (int)(l / HW_);
  float sc = scaleG[g*B_ + b];
  float4* Xp = (float4*)X;
  float4 v = Xp[i];
  v.x *= sc; v.y *= sc; v.z *= sc; v.w *= sc;
  Xp[i] = v;
}

// ------- outImg (+)= wts[widx]*scale[b]*((X (+X2)) or tgt*mask) -------
template<int MODE>   // 0: overwrite with tgt*mask ; 1: add (X + X2)
__global__ __launch_bounds__(256) void k_accum(
    const float* __restrict__ X, const float* __restrict__ X2,
    const float* __restrict__ maskB, const float* __restrict__ scaleG,
    const float* __restrict__ wts, float* __restrict__ outI, int widx) {
  long i = (long)blockIdx.x*256 + threadIdx.x;
  const long n4 = (long)HW_*B_*D_/4;
  if (i >= n4) return;
  long t = i >> 7;
  int b = (int)(t & 15);
  int hw = (int)(t >> 4);
  float w = wts[widx] * scaleG[b];
  if (MODE == 0) w *= maskB[hw*B_ + b];
  float4 v = ((const float4*)X)[i];
  if (MODE == 1 && X2) {
    float4 v2 = ((const float4*)X2)[i];
    v.x += v2.x; v.y += v2.y; v.z += v2.z; v.w += v2.w;
  }
  float4* Op = (float4*)outI;
  if (MODE == 0) {
    Op[i] = make_float4(v.x*w, v.y*w, v.z*w, v.w*w);
  } else {
    float4 o = Op[i];
    o.x += v.x*w; o.y += v.y*w; o.z += v.z*w; o.w += v.w*w;
    Op[i] = o;
  }
}

// =======================================================================
extern "C" void kernel_launch(void* const* d_in, const int* in_sizes, int n_in,
                              void* d_out, int out_size, void* d_ws, size_t ws_size,
                              hipStream_t stream) {
  (void)in_sizes; (void)n_in; (void)out_size; (void)ws_size;
  const float* train_feat = (const float*)d_in[0];
  const float* test_feat  = (const float*)d_in[1];
  const float* label      = (const float*)d_in[2];
  const float* sw  = (const float*)d_in[3];
  const float* sb  = (const float*)d_in[4];
  const float* cw  = (const float*)d_in[5];
  const float* cb  = (const float*)d_in[6];
  const float* qxm = (const float*)d_in[7];
  float* out = (float*)d_out;

  // ---- workspace layout (floats); ~343 MB total ----
  float* ws = (float*)d_ws;
  long o = 0;
  float* srcT  = ws + o; o += (long)M_*B_*D_;
  float* tstT  = ws + o; o += (long)M_*B_*D_;
  float* mem   = ws + o; o += (long)M_*B_*D_;
  float* wkMem = ws + o; o += (long)M_*B_*K_;
  float* wq    = ws + o; o += (long)M_*B_*K_;
  float* big   = ws + o; o += (long)B_*M_*M_;
  float* maskB = ws + o; o += HW_*B_;
  float* part  = ws + o; o += T_*B_*16;
  float* scaleG= ws + o; o += 64;
  float* wts   = ws + o; o += 4;
  // bf16 transposed-V buffers
  unsigned short* srcTT = (unsigned short*)(ws + o); o += (long)B_*D_*MP_M/2;  // reused as memTT
  unsigned short* imTT  = (unsigned short*)(ws + o); o += (long)B_*D_*MP_HW/2;
  unsigned short* tgtTT = (unsigned short*)(ws + o); o += (long)B_*D_*MP_HW/2;
  unsigned short* memTT = srcTT;   // srcTT dead after encoder AV

  // decoder sub-buffers inside `big`
  float* scoresC = big;                               // [B,HW,M]
  float* scoresS = scoresC + (long)B_*HW_*M_;         // [B,HW,HW]
  float* W2      = scoresS + (long)B_*HW_*HW_;        // [B,HW,HW]
  float* tgt     = W2      + (long)B_*HW_*HW_;        // [HW,B,D]
  float* Xbuf    = tgt     + (long)HW_*B_*D_;         // [HW,B,D]
  float* outImg  = Xbuf    + (long)HW_*B_*D_;         // [HW,B,D]

  const long imgN4 = (long)HW_*B_*D_/4;
  const int  imgBlocks = (int)((imgN4 + 255)/256);

  // ---- input transposes + qxm softmax ----
  k_transpose_in<<<dim3(16,16,T_*B_),256,0,stream>>>(train_feat, srcT);
  k_transpose_in<<<dim3(16,16,T_*B_),256,0,stream>>>(test_feat,  tstT);
  k_wts<<<1,64,0,stream>>>(qxm, wts);

  // ---- encoder: memory = inorm(src + selfattn(src), T) ----
  k_proj_l2n<<<(M_*B_+31)/32,256,0,stream>>>(srcT, sw, sb, wq, M_*B_);
  k_scores<8><<<dim3((M_+127)/128,(M_+127)/128,B_),256,0,stream>>>(wq, wq, big, M_, M_);
  k_softmax<<<B_*M_,256,0,stream>>>(big, M_);
  k_cvtT<<<dim3(MP_M/32, D_/32, B_),256,0,stream>>>(srcT, srcTT, M_, MP_M);
  k_av_mfma<false><<<dim3((M_+127)/128, D_/64, B_),256,0,stream>>>(
      big, srcTT, srcT, nullptr, mem, M_, M_, MP_M);
  k_ss_partial<false><<<dim3(T_*B_,16),256,0,stream>>>(mem, nullptr, nullptr, part);
  k_ss_final<<<1,64,0,stream>>>(part, scaleG, T_*B_);
  k_inorm_apply<<<(int)(((long)M_*B_*D_/4 + 255)/256),256,0,stream>>>(
      mem, scaleG, (long)M_*B_*D_/4);
  k_cvtT<<<dim3(MP_M/32, D_/32, B_),256,0,stream>>>(mem, memTT, M_, MP_M);
  k_proj_l2n<<<(M_*B_+31)/32,256,0,stream>>>(mem, cw, cb, wkMem, M_*B_);

  // ---- decoder: 3 train images then 3 test images ----
  for (int img = 0; img < 2*T_; img++) {
    const float* base = (img < T_) ? srcT + (long)img*HW_*B_*D_
                                   : tstT + (long)(img - T_)*HW_*B_*D_;
    float* outP = out + (long)img*B_*D_*HW_;

    // self-attention + inorm -> tgt
    k_proj_l2n<<<(HW_*B_+31)/32,256,0,stream>>>(base, sw, sb, wq, HW_*B_);
    k_cvtT<<<dim3(MP_HW/32, D_/32, B_),256,0,stream>>>(base, imTT, HW_, MP_HW);
    k_scores<4><<<dim3((HW_+127)/128,(HW_+63)/64,B_),256,0,stream>>>(
        wq, wq, scoresS, HW_, HW_);
    k_softmax<<<B_*HW_,256,0,stream>>>(scoresS, HW_);
    k_av_mfma<false><<<dim3((HW_+127)/128, D_/64, B_),256,0,stream>>>(
        scoresS, imTT, base, nullptr, tgt, HW_, HW_, MP_HW);
    k_ss_partial<false><<<dim3(B_,16),256,0,stream>>>(tgt, nullptr, nullptr, part);
    k_ss_final<<<1,64,0,stream>>>(part, scaleG, B_);
    k_inorm_apply<<<imgBlocks,256,0,stream>>>(tgt, scaleG, imgN4);
    k_cvtT<<<dim3(MP_HW/32, D_/32, B_),256,0,stream>>>(tgt, tgtTT, HW_, MP_HW);

    // shared cross-attention weights aff = softmax(30*wq(tgt)·wk(memory))
    k_proj_l2n<<<(HW_*B_+31)/32,256,0,stream>>>(tgt, cw, cb, wq, HW_*B_);
    k_scores<8><<<dim3((HW_+127)/128,(M_+127)/128,B_),256,0,stream>>>(
        wq, wkMem, scoresC, HW_, M_);
    k_softmax<<<B_*HW_,256,0,stream>>>(scoresC, M_);

    // W2 + mask (fused)
    k_w2m<<<B_*HW_,256,0,stream>>>(scoresC, label, W2, maskB);

    // t_base = inorm(tgt*mask):  out = w0*scale*tgt*mask
    k_ss_partial<true><<<dim3(B_,16),256,0,stream>>>(tgt, nullptr, maskB, part);
    k_ss_final<<<1,64,0,stream>>>(part, scaleG, B_);
    k_accum<0><<<imgBlocks,256,0,stream>>>(
        tgt, nullptr, maskB, scaleG, wts, outImg, 0);

    // t_q = inorm(W2@tgt + tgt):  out += w1*scale*X
    k_av_mfma<false><<<dim3((HW_+127)/128, D_/64, B_),256,0,stream>>>(
        W2, tgtTT, tgt, nullptr, Xbuf, HW_, HW_, MP_HW);
    k_ss_partial<false><<<dim3(B_,16),256,0,stream>>>(Xbuf, nullptr, nullptr, part);
    k_ss_final<<<1,64,0,stream>>>(part, scaleG, B_);
    k_accum<1><<<imgBlocks,256,0,stream>>>(
        Xbuf, nullptr, nullptr, scaleG, wts, outImg, 1);

    // t_v = inorm((aff*pos1)@memory + tgt):  out += w2*scale*X
    k_av_mfma<true><<<dim3((HW_+127)/128, D_/64, B_),256,0,stream>>>(
        scoresC, memTT, tgt, label, Xbuf, HW_, M_, MP_M);
    k_ss_partial<false><<<dim3(B_,16),256,0,stream>>>(Xbuf, nullptr, nullptr, part);
    k_ss_final<<<1,64,0,stream>>>(part, scaleG, B_);
    k_accum<1><<<imgBlocks,256,0,stream>>>(
        Xbuf, nullptr, nullptr, scaleG, wts, outImg, 2);

    k_out_store<<<dim3(16,16,B_),256,0,stream>>>(outImg, outP);
  }
}

// Round 12
// 4150.262 us; speedup vs baseline: 1.5423x; 1.2187x over previous
//
#include <hip/hip_runtime.h>

// ---------------- problem dims (fixed by reference) ----------------
#define T_   3
#define B_   16
#define D_   512
#define HW_  484
#define M_   1452          // T_*HW_
#define K_   128
#define TEMP_ 30.0f
#define EPS_  1e-5f
#define NORM_SCALE_ ((float)0.011048543456039806)
#define MP_M  1472         // M padded to multiple of 32 (bf16 VT buffers)
#define MP_HW 512          // HW padded to multiple of 32

typedef __attribute__((ext_vector_type(8))) short short8v;   // 8 bf16 (4 VGPRs)
typedef __attribute__((ext_vector_type(4))) float floatx4;   // MFMA C/D

// fp32 -> bf16 round-to-nearest-even
__device__ __forceinline__ unsigned short f2bf(float x) {
  unsigned int u = __float_as_uint(x);
  u += 0x7fffu + ((u >> 16) & 1u);
  return (unsigned short)(u >> 16);
}
__device__ __forceinline__ float bf2f(unsigned short h) {
  return __uint_as_float((unsigned int)h << 16);
}

// ---------------- block-reduce helpers (blockDim == 256) ----------------
__device__ __forceinline__ float blockReduceSum256(float v) {
  __shared__ float red[4];
  #pragma unroll
  for (int o = 32; o > 0; o >>= 1) v += __shfl_xor(v, o);
  if ((threadIdx.x & 63) == 0) red[threadIdx.x >> 6] = v;
  __syncthreads();
  float t = red[0] + red[1] + red[2] + red[3];
  __syncthreads();
  return t;
}

__device__ __forceinline__ float blockReduceMax256(float v) {
  __shared__ float redm[4];
  #pragma unroll
  for (int o = 32; o > 0; o >>= 1) v = fmaxf(v, __shfl_xor(v, o));
  if ((threadIdx.x & 63) == 0) redm[threadIdx.x >> 6] = v;
  __syncthreads();
  float t = fmaxf(fmaxf(redm[0], redm[1]), fmaxf(redm[2], redm[3]));
  __syncthreads();
  return t;
}

// ---------------- softmax(qxm) -> wts[3] ----------------
__global__ void k_wts(const float* __restrict__ qxm, float* __restrict__ wts) {
  if (threadIdx.x == 0 && blockIdx.x == 0) {
    float a = qxm[0], b = qxm[1], c = qxm[2];
    float m = fmaxf(a, fmaxf(b, c));
    float ea = __expf(a - m), eb = __expf(b - m), ec = __expf(c - m);
    float s = ea + eb + ec;
    wts[0] = ea / s; wts[1] = eb / s; wts[2] = ec / s;
  }
}

// ---------------- feat [TB, D, HW] -> X [t*HW+hw, b, d] ----------------
__global__ __launch_bounds__(256) void k_transpose_in(
    const float* __restrict__ in, float* __restrict__ out) {
  __shared__ float tile[32][33];
  const int tb = blockIdx.z;           // t*B_+b
  const int t = tb / B_, b = tb % B_;
  const int hw0 = blockIdx.x * 32, d0 = blockIdx.y * 32;
  const int tx = threadIdx.x & 31, ty = threadIdx.x >> 5;   // 32x8
  for (int i = ty; i < 32; i += 8) {
    int d = d0 + i, hw = hw0 + tx;
    tile[i][tx] = (hw < HW_) ? in[((long)tb*D_ + d)*HW_ + hw] : 0.f;
  }
  __syncthreads();
  for (int i = ty; i < 32; i += 8) {
    int hw = hw0 + i, d = d0 + tx;
    if (hw < HW_) out[(((long)t*HW_ + hw)*B_ + b)*D_ + d] = tile[tx][i];
  }
}

// ---------------- outImg [hw,b,d] -> out [b, d, hw] (per image) ----------------
__global__ __launch_bounds__(256) void k_out_store(
    const float* __restrict__ Xo, float* __restrict__ outP) {
  __shared__ float tile[32][33];
  const int b = blockIdx.z;
  const int hw0 = blockIdx.x * 32, d0 = blockIdx.y * 32;
  const int tx = threadIdx.x & 31, ty = threadIdx.x >> 5;
  for (int i = ty; i < 32; i += 8) {
    int hw = hw0 + i, d = d0 + tx;
    tile[i][tx] = (hw < HW_) ? Xo[((long)hw*B_ + b)*D_ + d] : 0.f;
  }
  __syncthreads();
  for (int i = ty; i < 32; i += 8) {
    int d = d0 + i, hw = hw0 + tx;
    if (hw < HW_) outP[((long)b*D_ + d)*HW_ + hw] = tile[tx][i];
  }
}

// ----- X [L, B, D] fp32 -> XT [B][D][Mp] bf16 (zero-padded l in [L,Mp)) -----
__global__ __launch_bounds__(256) void k_cvtT(
    const float* __restrict__ X, unsigned short* __restrict__ XT,
    int L, int Mp) {
  __shared__ float tile[32][33];     // [d-idx][l-idx]
  const int b = blockIdx.z;
  const int l0 = blockIdx.x * 32, d0 = blockIdx.y * 32;
  const int tx = threadIdx.x & 31, ty = threadIdx.x >> 5;
  for (int i = ty; i < 32; i += 8) {
    int l = l0 + i;
    float v = 0.f;
    if (l < L) v = X[((long)l*B_ + b)*D_ + d0 + tx];   // coalesced in d
    tile[tx][i] = v;
  }
  __syncthreads();
  const int di = threadIdx.x >> 3, quad = threadIdx.x & 7;  // 4 l per thread
  ushort4 w;
  w.x = f2bf(tile[di][4*quad+0]);
  w.y = f2bf(tile[di][4*quad+1]);
  w.z = f2bf(tile[di][4*quad+2]);
  w.w = f2bf(tile[di][4*quad+3]);
  *(ushort4*)&XT[((long)b*D_ + d0 + di)*Mp + l0 + 4*quad] = w;
}

// ----- Y[l,b,:] = l2norm(X[l,b,:] @ W^T + bias) -> hi/lo bf16 pair -----
__global__ __launch_bounds__(256) void k_proj_l2n(
    const float* __restrict__ X, const float* __restrict__ Wm,
    const float* __restrict__ bias,
    unsigned short* __restrict__ Yh, unsigned short* __restrict__ Yl,
    int nRows) {
  __shared__ __align__(16) float sX[32][68];
  __shared__ __align__(16) float sW[128][68];
  const int tid = threadIdx.x;
  const int rp = tid >> 4;        // 0..15 row-pair
  const int kg = tid & 15;        // 0..15
  const int row0 = blockIdx.x * 32;
  float acc[2][8] = {};
  for (int dc = 0; dc < D_; dc += 64) {
    for (int f = tid; f < 32*16; f += 256) {
      int rr = f >> 4, c4 = (f & 15) * 4;
      int rg = row0 + rr;
      float4 v = make_float4(0.f, 0.f, 0.f, 0.f);
      if (rg < nRows) v = *(const float4*)&X[(long)rg*D_ + dc + c4];
      *(float4*)&sX[rr][c4] = v;
    }
    for (int f = tid; f < 128*16; f += 256) {
      int rr = f >> 4, c4 = (f & 15) * 4;
      *(float4*)&sW[rr][c4] = *(const float4*)&Wm[rr*D_ + dc + c4];
    }
    __syncthreads();
    #pragma unroll
    for (int d4 = 0; d4 < 64; d4 += 4) {
      float4 xa = *(const float4*)&sX[rp*2+0][d4];
      float4 xb = *(const float4*)&sX[rp*2+1][d4];
      #pragma unroll
      for (int i = 0; i < 8; i++) {
        float4 w = *(const float4*)&sW[kg + 16*i][d4];
        acc[0][i] += xa.x*w.x + xa.y*w.y + xa.z*w.z + xa.w*w.w;
        acc[1][i] += xb.x*w.x + xb.y*w.y + xb.z*w.z + xb.w*w.w;
      }
    }
    __syncthreads();
  }
  #pragma unroll
  for (int r = 0; r < 2; r++) {
    float ss = 0.f;
    #pragma unroll
    for (int i = 0; i < 8; i++) {
      acc[r][i] += bias[kg + 16*i];
      ss += acc[r][i] * acc[r][i];
    }
    ss += __shfl_xor(ss, 1); ss += __shfl_xor(ss, 2);
    ss += __shfl_xor(ss, 4); ss += __shfl_xor(ss, 8);
    float inv = 1.f / fmaxf(sqrtf(ss), 1e-12f);
    int rg = row0 + rp*2 + r;
    if (rg < nRows) {
      #pragma unroll
      for (int i = 0; i < 8; i++) {
        float y = acc[r][i] * inv;
        unsigned short h = f2bf(y);
        unsigned short l = f2bf(y - bf2f(h));
        Yh[(long)rg*K_ + kg + 16*i] = h;
        Yl[(long)rg*K_ + kg + 16*i] = l;
      }
    }
  }
}

// ===== MFMA scores: S[b,q,j] = TEMP * sum_e Q[q,b,e]*K[j,b,e] (hi/lo bf16) =====
// 3-term split: qh*kh + qh*kl + ql*kh  (~fp32 accuracy; lo*lo dropped).
// Block 256 thr = 4 waves; tile 128q x 64j; wave w: q rows 32w..32w+32.
__global__ __launch_bounds__(256) void k_scores_mfma(
    const unsigned short* __restrict__ Qh, const unsigned short* __restrict__ Ql,
    const unsigned short* __restrict__ Kh, const unsigned short* __restrict__ Kl,
    float* __restrict__ S, int Lq, int Lk) {
  __shared__ __align__(16) unsigned short sQh[128][40], sQl[128][40];
  __shared__ __align__(16) unsigned short sKh[64][40],  sKl[64][40];
  const int b = blockIdx.z;
  const int q0 = blockIdx.x * 128, j0 = blockIdx.y * 64;
  const int tid = threadIdx.x, wid = tid >> 6, lane = tid & 63;
  floatx4 acc[2][4];
  #pragma unroll
  for (int i = 0; i < 2; i++)
    #pragma unroll
    for (int j = 0; j < 4; j++)
      acc[i][j] = (floatx4){0.f, 0.f, 0.f, 0.f};

  const int qr = tid >> 1, qh16 = (tid & 1) * 16;   // Q stage: 128 rows x 16e
  const int kr = tid >> 2, kq8 = (tid & 3) * 8;     // K stage: 64 rows x 8e

  for (int e0 = 0; e0 < K_; e0 += 32) {
    // --- stage Q [128][32] hi+lo ---
    {
      int qg = q0 + qr;
      if (qg < Lq) {
        const unsigned short* ph = &Qh[((long)qg*B_ + b)*K_ + e0 + qh16];
        const unsigned short* pl = &Ql[((long)qg*B_ + b)*K_ + e0 + qh16];
        *(uint4*)&sQh[qr][qh16]     = *(const uint4*)ph;
        *(uint4*)&sQh[qr][qh16 + 8] = *(const uint4*)(ph + 8);
        *(uint4*)&sQl[qr][qh16]     = *(const uint4*)pl;
        *(uint4*)&sQl[qr][qh16 + 8] = *(const uint4*)(pl + 8);
      } else {
        uint4 z = make_uint4(0,0,0,0);
        *(uint4*)&sQh[qr][qh16] = z; *(uint4*)&sQh[qr][qh16 + 8] = z;
        *(uint4*)&sQl[qr][qh16] = z; *(uint4*)&sQl[qr][qh16 + 8] = z;
      }
    }
    // --- stage K [64][32] hi+lo ---
    {
      int jg = j0 + kr;
      if (jg < Lk) {
        *(uint4*)&sKh[kr][kq8] = *(const uint4*)&Kh[((long)jg*B_ + b)*K_ + e0 + kq8];
        *(uint4*)&sKl[kr][kq8] = *(const uint4*)&Kl[((long)jg*B_ + b)*K_ + e0 + kq8];
      } else {
        uint4 z = make_uint4(0,0,0,0);
        *(uint4*)&sKh[kr][kq8] = z; *(uint4*)&sKl[kr][kq8] = z;
      }
    }
    __syncthreads();
    {
      const int arow = lane & 15;
      const int kof = (lane >> 4) * 8;
      short8v ah0 = *(const short8v*)&sQh[32*wid + arow][kof];
      short8v ah1 = *(const short8v*)&sQh[32*wid + 16 + arow][kof];
      short8v al0 = *(const short8v*)&sQl[32*wid + arow][kof];
      short8v al1 = *(const short8v*)&sQl[32*wid + 16 + arow][kof];
      #pragma unroll
      for (int td = 0; td < 4; ++td) {
        short8v bh = *(const short8v*)&sKh[16*td + arow][kof];
        short8v bl = *(const short8v*)&sKl[16*td + arow][kof];
        acc[0][td] = __builtin_amdgcn_mfma_f32_16x16x32_bf16(ah0, bh, acc[0][td], 0, 0, 0);
        acc[0][td] = __builtin_amdgcn_mfma_f32_16x16x32_bf16(ah0, bl, acc[0][td], 0, 0, 0);
        acc[0][td] = __builtin_amdgcn_mfma_f32_16x16x32_bf16(al0, bh, acc[0][td], 0, 0, 0);
        acc[1][td] = __builtin_amdgcn_mfma_f32_16x16x32_bf16(ah1, bh, acc[1][td], 0, 0, 0);
        acc[1][td] = __builtin_amdgcn_mfma_f32_16x16x32_bf16(ah1, bl, acc[1][td], 0, 0, 0);
        acc[1][td] = __builtin_amdgcn_mfma_f32_16x16x32_bf16(al1, bh, acc[1][td], 0, 0, 0);
      }
    }
    __syncthreads();
  }
  // epilogue: D row=(lane>>4)*4+r (q), col=lane&15 (j)
  const int col = lane & 15, row4 = (lane >> 4) * 4;
  #pragma unroll
  for (int tq = 0; tq < 2; ++tq) {
    #pragma unroll
    for (int r = 0; r < 4; ++r) {
      int q = q0 + 32*wid + 16*tq + row4 + r;
      if (q >= Lq) continue;
      float* row = S + ((long)b*Lq + q)*Lk;
      #pragma unroll
      for (int td = 0; td < 4; ++td) {
        int j = j0 + 16*td + col;
        if (j < Lk) row[j] = TEMP_ * acc[tq][td][r];
      }
    }
  }
}

// ---------------- row softmax in place; len % 4 == 0, len <= 1452 ----------------
__global__ __launch_bounds__(256) void k_softmax(float* __restrict__ S, int len) {
  __shared__ __align__(16) float buf[1456];
  const long row = blockIdx.x;
  float* p = S + row * (long)len;
  const int tid = threadIdx.x;
  float mx = -1e30f;
  for (int i = tid*4; i < len; i += 1024) {
    float4 v = *(const float4*)&p[i];
    *(float4*)&buf[i] = v;
    mx = fmaxf(mx, fmaxf(fmaxf(v.x, v.y), fmaxf(v.z, v.w)));
  }
  mx = blockReduceMax256(mx);
  float sum = 0.f;
  for (int i = tid*4; i < len; i += 1024) {
    float4 v = *(float4*)&buf[i];
    v.x = __expf(v.x - mx); v.y = __expf(v.y - mx);
    v.z = __expf(v.z - mx); v.w = __expf(v.w - mx);
    sum += v.x + v.y + v.z + v.w;
    *(float4*)&buf[i] = v;
  }
  sum = blockReduceSum256(sum);
  float inv = 1.f / sum;
  for (int i = tid*4; i < len; i += 1024) {
    float4 v = *(float4*)&buf[i];
    v.x *= inv; v.y *= inv; v.z *= inv; v.w *= inv;
    *(float4*)&p[i] = v;
  }
}

// ========== MFMA AV: dst[q,b,d] = sum_k S[b,q,k]*(pos1_k)*V[k,b,d] (+R) ==========
template<bool SCALE>
__global__ __launch_bounds__(256) void k_av_mfma(
    const float* __restrict__ S, const unsigned short* __restrict__ VT,
    const float* __restrict__ R, const float* __restrict__ label,
    float* __restrict__ dst, int Lq, int Lk, int Mp) {
  __shared__ __align__(16) unsigned short sS[128][40];   // 32 bf16 + pad (80 B rows)
  __shared__ __align__(16) unsigned short sV[64][40];
  const int b = blockIdx.z;
  const int q0 = blockIdx.x * 128, d0 = blockIdx.y * 64;
  const int tid = threadIdx.x;
  const int wid = tid >> 6, lane = tid & 63;
  floatx4 acc[2][4];
  #pragma unroll
  for (int i = 0; i < 2; i++)
    #pragma unroll
    for (int j = 0; j < 4; j++)
      acc[i][j] = (floatx4){0.f, 0.f, 0.f, 0.f};

  const int srr = tid >> 1, shalf = tid & 1;   // S stage: row, 16-col half
  const int vdr = tid >> 2, vq = tid & 3;      // V stage: row, 16B quarter
  const int nch = (Lk + 31) / 32;

  for (int c = 0; c < nch; ++c) {
    const int k0 = c * 32;
    // --- stage S tile [128 q][32 k] fp32 -> bf16 (optional pos1 scale) ---
    {
      int qg = q0 + srr;
      unsigned short outv[16];
      #pragma unroll
      for (int u = 0; u < 4; ++u) {
        int kk = k0 + 16*shalf + 4*u;
        float4 v = make_float4(0.f, 0.f, 0.f, 0.f);
        if (qg < Lq && kk < Lk) v = *(const float4*)&S[((long)b*Lq + qg)*Lk + kk];
        if (SCALE) {
          float* pv = (float*)&v;
          #pragma unroll
          for (int e = 0; e < 4; ++e) {
            int kj = kk + e;
            if (kj < Lk) {
              int pp = kj / HW_, hh = kj - pp*HW_;
              pv[e] *= label[(pp*B_ + b)*HW_ + hh];
            }
          }
        }
        outv[4*u+0] = f2bf(v.x); outv[4*u+1] = f2bf(v.y);
        outv[4*u+2] = f2bf(v.z); outv[4*u+3] = f2bf(v.w);
      }
      *(uint4*)&sS[srr][16*shalf]     = *(uint4*)&outv[0];
      *(uint4*)&sS[srr][16*shalf + 8] = *(uint4*)&outv[8];
    }
    // --- stage V tile [64 d][32 k] bf16 from global VT (k-padded, in-bounds) ---
    {
      uint4 v = *(const uint4*)&VT[((long)b*D_ + d0 + vdr)*Mp + k0 + 8*vq];
      *(uint4*)&sV[vdr][8*vq] = v;
    }
    __syncthreads();
    {
      const int arow = lane & 15;
      const int kof = (lane >> 4) * 8;
      short8v a0 = *(const short8v*)&sS[32*wid + arow][kof];
      short8v a1 = *(const short8v*)&sS[32*wid + 16 + arow][kof];
      #pragma unroll
      for (int td = 0; td < 4; ++td) {
        short8v bf = *(const short8v*)&sV[16*td + arow][kof];
        acc[0][td] = __builtin_amdgcn_mfma_f32_16x16x32_bf16(a0, bf, acc[0][td], 0, 0, 0);
        acc[1][td] = __builtin_amdgcn_mfma_f32_16x16x32_bf16(a1, bf, acc[1][td], 0, 0, 0);
      }
    }
    __syncthreads();
  }
  // --- epilogue: D[row][col], row=(lane>>4)*4+r, col=lane&15 ---
  const int col = lane & 15, row4 = (lane >> 4) * 4;
  #pragma unroll
  for (int tq = 0; tq < 2; ++tq) {
    #pragma unroll
    for (int r = 0; r < 4; ++r) {
      int q = q0 + 32*wid + 16*tq + row4 + r;
      if (q >= Lq) continue;
      long base = ((long)q*B_ + b)*D_ + d0 + col;
      #pragma unroll
      for (int td = 0; td < 4; ++td) {
        float v = acc[tq][td][r];
        long idx = base + 16*td;
        if (R) v += R[idx];
        dst[idx] = v;
      }
    }
  }
}

// ------- fused: W2[b,q,k] = sum_p SC[b,q,p*HW+k]*label[p,b,k]; mask = row-sum ----
__global__ __launch_bounds__(256) void k_w2m(
    const float* __restrict__ SC, const float* __restrict__ label,
    float* __restrict__ W2, float* __restrict__ maskB) {
  const int row = blockIdx.x;            // b*HW_+q
  const int b = row / HW_;
  const int q = row - b*HW_;
  const float* srow = SC + (long)row * M_;
  float s = 0.f;
  for (int k = threadIdx.x; k < HW_; k += 256) {
    float w = srow[k]         * label[(0*B_ + b)*HW_ + k]
            + srow[HW_ + k]   * label[(1*B_ + b)*HW_ + k]
            + srow[2*HW_ + k] * label[(2*B_ + b)*HW_ + k];
    W2[(long)row*HW_ + k] = w;
    s += w;
  }
  s = blockReduceSum256(s);
  if (threadIdx.x == 0) maskB[q*B_ + b] = s;
}

// ------- inorm pass 1: partial sums of squares per (g,b), 16 chunks -------
template<bool WM>
__global__ __launch_bounds__(256) void k_ss_partial(
    const float* __restrict__ X, const float* __restrict__ X2,
    const float* __restrict__ maskB, float* __restrict__ part) {
  const int gb = blockIdx.x;           // g*B_+b
  const int c = blockIdx.y;            // 0..15
  const int g = gb / B_, b = gb % B_;
  const float4* Xp = (const float4*)X;
  const float4* X2p = (const float4*)X2;
  const int CH = (HW_*D_/4) / 16;
  float s = 0.f;
  for (int i = c*CH + threadIdx.x; i < (c+1)*CH; i += 256) {
    int hw = i >> 7;
    int d4 = i & 127;
    long idx = (((long)g*HW_ + hw)*B_ + b)*(D_/4) + d4;
    float4 v = Xp[idx];
    if (X2p) {
      float4 v2 = X2p[idx];
      v.x += v2.x; v.y += v2.y; v.z += v2.z; v.w += v2.w;
    }
    float m = 1.f;
    if (WM) m = maskB[hw*B_ + b];
    float a = v.x*m, e = v.y*m, f = v.z*m, h = v.w*m;
    s += a*a + e*e + f*f + h*h;
  }
  s = blockReduceSum256(s);
  if (threadIdx.x == 0) part[gb*16 + c] = s;
}

// ------- inorm pass 2: scale factor per group -------
__global__ void k_ss_final(const float* __restrict__ part,
                           float* __restrict__ scaleG, int nG) {
  int g = threadIdx.x;
  if (g < nG) {
    float s = 0.f;
    #pragma unroll
    for (int c = 0; c < 16; c++) s += part[g*16 + c];
    scaleG[g] = NORM_SCALE_ * sqrtf((float)(D_*HW_) / (s + EPS_));
  }
}

// ------- x *= scaleG[g*B+b], x is [G*HW, B, D] viewed as float4 -------
__global__ __launch_bounds__(256) void k_inorm_apply(
    float* __restrict__ X, const float* __restrict__ scaleG, long n4) {
  long i = (long)blockIdx.x*256 + threadIdx.x;
  if (i >= n4) return;
  long t = i >> 7;
  int b = (int)(t & 15);
  long l = t >> 4;
  int g = (int)(l / HW_);
  float sc = scaleG[g*B_ + b];
  float4* Xp = (float4*)X;
  float4 v = Xp[i];
  v.x *= sc; v.y *= sc; v.z *= sc; v.w *= sc;
  Xp[i] = v;
}

// ------- outImg (+)= wts[widx]*scale[b]*((X (+X2)) or tgt*mask) -------
template<int MODE>   // 0: overwrite with tgt*mask ; 1: add (X + X2)
__global__ __launch_bounds__(256) void k_accum(
    const float* __restrict__ X, const float* __restrict__ X2,
    const float* __restrict__ maskB, const float* __restrict__ scaleG,
    const float* __restrict__ wts, float* __restrict__ outI, int widx) {
  long i = (long)blockIdx.x*256 + threadIdx.x;
  const long n4 = (long)HW_*B_*D_/4;
  if (i >= n4) return;
  long t = i >> 7;
  int b = (int)(t & 15);
  int hw = (int)(t >> 4);
  float w = wts[widx] * scaleG[b];
  if (MODE == 0) w *= maskB[hw*B_ + b];
  float4 v = ((const float4*)X)[i];
  if (MODE == 1 && X2) {
    float4 v2 = ((const float4*)X2)[i];
    v.x += v2.x; v.y += v2.y; v.z += v2.z; v.w += v2.w;
  }
  float4* Op = (float4*)outI;
  if (MODE == 0) {
    Op[i] = make_float4(v.x*w, v.y*w, v.z*w, v.w*w);
  } else {
    float4 o = Op[i];
    o.x += v.x*w; o.y += v.y*w; o.z += v.z*w; o.w += v.w*w;
    Op[i] = o;
  }
}

// =======================================================================
extern "C" void kernel_launch(void* const* d_in, const int* in_sizes, int n_in,
                              void* d_out, int out_size, void* d_ws, size_t ws_size,
                              hipStream_t stream) {
  (void)in_sizes; (void)n_in; (void)out_size; (void)ws_size;
  const float* train_feat = (const float*)d_in[0];
  const float* test_feat  = (const float*)d_in[1];
  const float* label      = (const float*)d_in[2];
  const float* sw  = (const float*)d_in[3];
  const float* sb  = (const float*)d_in[4];
  const float* cw  = (const float*)d_in[5];
  const float* cb  = (const float*)d_in[6];
  const float* qxm = (const float*)d_in[7];
  float* out = (float*)d_out;

  // ---- workspace layout (floats); ~343 MB total ----
  float* ws = (float*)d_ws;
  long o = 0;
  float* srcT  = ws + o; o += (long)M_*B_*D_;
  float* tstT  = ws + o; o += (long)M_*B_*D_;
  float* mem   = ws + o; o += (long)M_*B_*D_;
  // hi/lo bf16 projection buffers (each M*B*K ushorts = M*B*K/2 floats)
  unsigned short* wqh = (unsigned short*)(ws + o); o += (long)M_*B_*K_/2;
  unsigned short* wql = (unsigned short*)(ws + o); o += (long)M_*B_*K_/2;
  unsigned short* wkh = (unsigned short*)(ws + o); o += (long)M_*B_*K_/2;
  unsigned short* wkl = (unsigned short*)(ws + o); o += (long)M_*B_*K_/2;
  float* big   = ws + o; o += (long)B_*M_*M_;
  float* maskB = ws + o; o += HW_*B_;
  float* part  = ws + o; o += T_*B_*16;
  float* scaleG= ws + o; o += 64;
  float* wts   = ws + o; o += 4;
  // bf16 transposed-V buffers
  unsigned short* srcTT = (unsigned short*)(ws + o); o += (long)B_*D_*MP_M/2;  // reused as memTT
  unsigned short* imTT  = (unsigned short*)(ws + o); o += (long)B_*D_*MP_HW/2;
  unsigned short* tgtTT = (unsigned short*)(ws + o); o += (long)B_*D_*MP_HW/2;
  unsigned short* memTT = srcTT;   // srcTT dead after encoder AV

  // decoder sub-buffers inside `big`
  float* scoresC = big;                               // [B,HW,M]
  float* scoresS = scoresC + (long)B_*HW_*M_;         // [B,HW,HW]
  float* W2      = scoresS + (long)B_*HW_*HW_;        // [B,HW,HW]
  float* tgt     = W2      + (long)B_*HW_*HW_;        // [HW,B,D]
  float* Xbuf    = tgt     + (long)HW_*B_*D_;         // [HW,B,D]
  float* outImg  = Xbuf    + (long)HW_*B_*D_;         // [HW,B,D]

  const long imgN4 = (long)HW_*B_*D_/4;
  const int  imgBlocks = (int)((imgN4 + 255)/256);

  // ---- input transposes + qxm softmax ----
  k_transpose_in<<<dim3(16,16,T_*B_),256,0,stream>>>(train_feat, srcT);
  k_transpose_in<<<dim3(16,16,T_*B_),256,0,stream>>>(test_feat,  tstT);
  k_wts<<<1,64,0,stream>>>(qxm, wts);

  // ---- encoder: memory = inorm(src + selfattn(src), T) ----
  k_proj_l2n<<<(M_*B_+31)/32,256,0,stream>>>(srcT, sw, sb, wqh, wql, M_*B_);
  k_scores_mfma<<<dim3((M_+127)/128,(M_+63)/64,B_),256,0,stream>>>(
      wqh, wql, wqh, wql, big, M_, M_);
  k_softmax<<<B_*M_,256,0,stream>>>(big, M_);
  k_cvtT<<<dim3(MP_M/32, D_/32, B_),256,0,stream>>>(srcT, srcTT, M_, MP_M);
  k_av_mfma<false><<<dim3((M_+127)/128, D_/64, B_),256,0,stream>>>(
      big, srcTT, srcT, nullptr, mem, M_, M_, MP_M);
  k_ss_partial<false><<<dim3(T_*B_,16),256,0,stream>>>(mem, nullptr, nullptr, part);
  k_ss_final<<<1,64,0,stream>>>(part, scaleG, T_*B_);
  k_inorm_apply<<<(int)(((long)M_*B_*D_/4 + 255)/256),256,0,stream>>>(
      mem, scaleG, (long)M_*B_*D_/4);
  k_cvtT<<<dim3(MP_M/32, D_/32, B_),256,0,stream>>>(mem, memTT, M_, MP_M);
  k_proj_l2n<<<(M_*B_+31)/32,256,0,stream>>>(mem, cw, cb, wkh, wkl, M_*B_);

  // ---- decoder: 3 train images then 3 test images ----
  for (int img = 0; img < 2*T_; img++) {
    const float* base = (img < T_) ? srcT + (long)img*HW_*B_*D_
                                   : tstT + (long)(img - T_)*HW_*B_*D_;
    float* outP = out + (long)img*B_*D_*HW_;

    // self-attention + inorm -> tgt
    k_proj_l2n<<<(HW_*B_+31)/32,256,0,stream>>>(base, sw, sb, wqh, wql, HW_*B_);
    k_cvtT<<<dim3(MP_HW/32, D_/32, B_),256,0,stream>>>(base, imTT, HW_, MP_HW);
    k_scores_mfma<<<dim3((HW_+127)/128,(HW_+63)/64,B_),256,0,stream>>>(
        wqh, wql, wqh, wql, scoresS, HW_, HW_);
    k_softmax<<<B_*HW_,256,0,stream>>>(scoresS, HW_);
    k_av_mfma<false><<<dim3((HW_+127)/128, D_/64, B_),256,0,stream>>>(
        scoresS, imTT, base, nullptr, tgt, HW_, HW_, MP_HW);
    k_ss_partial<false><<<dim3(B_,16),256,0,stream>>>(tgt, nullptr, nullptr, part);
    k_ss_final<<<1,64,0,stream>>>(part, scaleG, B_);
    k_inorm_apply<<<imgBlocks,256,0,stream>>>(tgt, scaleG, imgN4);
    k_cvtT<<<dim3(MP_HW/32, D_/32, B_),256,0,stream>>>(tgt, tgtTT, HW_, MP_HW);

    // shared cross-attention weights aff = softmax(30*wq(tgt)·wk(memory))
    k_proj_l2n<<<(HW_*B_+31)/32,256,0,stream>>>(tgt, cw, cb, wqh, wql, HW_*B_);
    k_scores_mfma<<<dim3((HW_+127)/128,(M_+63)/64,B_),256,0,stream>>>(
        wqh, wql, wkh, wkl, scoresC, HW_, M_);
    k_softmax<<<B_*HW_,256,0,stream>>>(scoresC, M_);

    // W2 + mask (fused)
    k_w2m<<<B_*HW_,256,0,stream>>>(scoresC, label, W2, maskB);

    // t_base = inorm(tgt*mask):  out = w0*scale*tgt*mask
    k_ss_partial<true><<<dim3(B_,16),256,0,stream>>>(tgt, nullptr, maskB, part);
    k_ss_final<<<1,64,0,stream>>>(part, scaleG, B_);
    k_accum<0><<<imgBlocks,256,0,stream>>>(
        tgt, nullptr, maskB, scaleG, wts, outImg, 0);

    // t_q = inorm(W2@tgt + tgt):  out += w1*scale*X
    k_av_mfma<false><<<dim3((HW_+127)/128, D_/64, B_),256,0,stream>>>(
        W2, tgtTT, tgt, nullptr, Xbuf, HW_, HW_, MP_HW);
    k_ss_partial<false><<<dim3(B_,16),256,0,stream>>>(Xbuf, nullptr, nullptr, part);
    k_ss_final<<<1,64,0,stream>>>(part, scaleG, B_);
    k_accum<1><<<imgBlocks,256,0,stream>>>(
        Xbuf, nullptr, nullptr, scaleG, wts, outImg, 1);

    // t_v = inorm((aff*pos1)@memory + tgt):  out += w2*scale*X
    k_av_mfma<true><<<dim3((HW_+127)/128, D_/64, B_),256,0,stream>>>(
        scoresC, memTT, tgt, label, Xbuf, HW_, M_, MP_M);
    k_ss_partial<false><<<dim3(B_,16),256,0,stream>>>(Xbuf, nullptr, nullptr, part);
    k_ss_final<<<1,64,0,stream>>>(part, scaleG, B_);
    k_accum<1><<<imgBlocks,256,0,stream>>>(
        Xbuf, nullptr, nullptr, scaleG, wts, outImg, 2);

    k_out_store<<<dim3(16,16,B_),256,0,stream>>>(outImg, outP);
  }
}

// Round 13
// 3778.637 us; speedup vs baseline: 1.6940x; 1.0983x over previous
//
#include <hip/hip_runtime.h>

// ---------------- problem dims (fixed by reference) ----------------
#define T_   3
#define B_   16
#define D_   512
#define HW_  484
#define M_   1452          // T_*HW_
#define K_   128
#define TEMP_ 30.0f
#define EPS_  1e-5f
#define NORM_SCALE_ ((float)0.011048543456039806)
#define MP_M  1472         // M padded to multiple of 32 (bf16 VT buffers)
#define MP_HW 512          // HW padded to multiple of 32

typedef __attribute__((ext_vector_type(8))) short short8v;   // 8 bf16 (4 VGPRs)
typedef __attribute__((ext_vector_type(4))) float floatx4;   // MFMA C/D

// fp32 -> bf16 round-to-nearest-even
__device__ __forceinline__ unsigned short f2bf(float x) {
  unsigned int u = __float_as_uint(x);
  u += 0x7fffu + ((u >> 16) & 1u);
  return (unsigned short)(u >> 16);
}
__device__ __forceinline__ float bf2f(unsigned short h) {
  return __uint_as_float((unsigned int)h << 16);
}

// ---------------- block-reduce helpers (blockDim == 256) ----------------
__device__ __forceinline__ float blockReduceSum256(float v) {
  __shared__ float red[4];
  #pragma unroll
  for (int o = 32; o > 0; o >>= 1) v += __shfl_xor(v, o);
  if ((threadIdx.x & 63) == 0) red[threadIdx.x >> 6] = v;
  __syncthreads();
  float t = red[0] + red[1] + red[2] + red[3];
  __syncthreads();
  return t;
}

__device__ __forceinline__ float blockReduceMax256(float v) {
  __shared__ float redm[4];
  #pragma unroll
  for (int o = 32; o > 0; o >>= 1) v = fmaxf(v, __shfl_xor(v, o));
  if ((threadIdx.x & 63) == 0) redm[threadIdx.x >> 6] = v;
  __syncthreads();
  float t = fmaxf(fmaxf(redm[0], redm[1]), fmaxf(redm[2], redm[3]));
  __syncthreads();
  return t;
}

// ---------------- softmax(qxm) -> wts[3] ----------------
__global__ void k_wts(const float* __restrict__ qxm, float* __restrict__ wts) {
  if (threadIdx.x == 0 && blockIdx.x == 0) {
    float a = qxm[0], b = qxm[1], c = qxm[2];
    float m = fmaxf(a, fmaxf(b, c));
    float ea = __expf(a - m), eb = __expf(b - m), ec = __expf(c - m);
    float s = ea + eb + ec;
    wts[0] = ea / s; wts[1] = eb / s; wts[2] = ec / s;
  }
}

// ---------------- feat [TB, D, HW] -> X [t*HW+hw, b, d] ----------------
__global__ __launch_bounds__(256) void k_transpose_in(
    const float* __restrict__ in, float* __restrict__ out) {
  __shared__ float tile[32][33];
  const int tb = blockIdx.z;           // t*B_+b
  const int t = tb / B_, b = tb % B_;
  const int hw0 = blockIdx.x * 32, d0 = blockIdx.y * 32;
  const int tx = threadIdx.x & 31, ty = threadIdx.x >> 5;   // 32x8
  for (int i = ty; i < 32; i += 8) {
    int d = d0 + i, hw = hw0 + tx;
    tile[i][tx] = (hw < HW_) ? in[((long)tb*D_ + d)*HW_ + hw] : 0.f;
  }
  __syncthreads();
  for (int i = ty; i < 32; i += 8) {
    int hw = hw0 + i, d = d0 + tx;
    if (hw < HW_) out[(((long)t*HW_ + hw)*B_ + b)*D_ + d] = tile[tx][i];
  }
}

// ---------------- outImg [hw,b,d] -> out [b, d, hw] (per image) ----------------
__global__ __launch_bounds__(256) void k_out_store(
    const float* __restrict__ Xo, float* __restrict__ outP) {
  __shared__ float tile[32][33];
  const int b = blockIdx.z;
  const int hw0 = blockIdx.x * 32, d0 = blockIdx.y * 32;
  const int tx = threadIdx.x & 31, ty = threadIdx.x >> 5;
  for (int i = ty; i < 32; i += 8) {
    int hw = hw0 + i, d = d0 + tx;
    tile[i][tx] = (hw < HW_) ? Xo[((long)hw*B_ + b)*D_ + d] : 0.f;
  }
  __syncthreads();
  for (int i = ty; i < 32; i += 8) {
    int d = d0 + i, hw = hw0 + tx;
    if (hw < HW_) outP[((long)b*D_ + d)*HW_ + hw] = tile[tx][i];
  }
}

// ----- X [L, B, D] fp32 -> XT [B][D][Mp] bf16 (zero-padded l in [L,Mp)) -----
__global__ __launch_bounds__(256) void k_cvtT(
    const float* __restrict__ X, unsigned short* __restrict__ XT,
    int L, int Mp) {
  __shared__ float tile[32][33];     // [d-idx][l-idx]
  const int b = blockIdx.z;
  const int l0 = blockIdx.x * 32, d0 = blockIdx.y * 32;
  const int tx = threadIdx.x & 31, ty = threadIdx.x >> 5;
  for (int i = ty; i < 32; i += 8) {
    int l = l0 + i;
    float v = 0.f;
    if (l < L) v = X[((long)l*B_ + b)*D_ + d0 + tx];   // coalesced in d
    tile[tx][i] = v;
  }
  __syncthreads();
  const int di = threadIdx.x >> 3, quad = threadIdx.x & 7;  // 4 l per thread
  ushort4 w;
  w.x = f2bf(tile[di][4*quad+0]);
  w.y = f2bf(tile[di][4*quad+1]);
  w.z = f2bf(tile[di][4*quad+2]);
  w.w = f2bf(tile[di][4*quad+3]);
  *(ushort4*)&XT[((long)b*D_ + d0 + di)*Mp + l0 + 4*quad] = w;
}

// ----- Y[l,b,:] = l2norm(X[l,b,:] @ W^T + bias) -> hi/lo bf16 pair -----
__global__ __launch_bounds__(256) void k_proj_l2n(
    const float* __restrict__ X, const float* __restrict__ Wm,
    const float* __restrict__ bias,
    unsigned short* __restrict__ Yh, unsigned short* __restrict__ Yl,
    int nRows) {
  __shared__ __align__(16) float sX[32][68];
  __shared__ __align__(16) float sW[128][68];
  const int tid = threadIdx.x;
  const int rp = tid >> 4;        // 0..15 row-pair
  const int kg = tid & 15;        // 0..15
  const int row0 = blockIdx.x * 32;
  float acc[2][8] = {};
  for (int dc = 0; dc < D_; dc += 64) {
    for (int f = tid; f < 32*16; f += 256) {
      int rr = f >> 4, c4 = (f & 15) * 4;
      int rg = row0 + rr;
      float4 v = make_float4(0.f, 0.f, 0.f, 0.f);
      if (rg < nRows) v = *(const float4*)&X[(long)rg*D_ + dc + c4];
      *(float4*)&sX[rr][c4] = v;
    }
    for (int f = tid; f < 128*16; f += 256) {
      int rr = f >> 4, c4 = (f & 15) * 4;
      *(float4*)&sW[rr][c4] = *(const float4*)&Wm[rr*D_ + dc + c4];
    }
    __syncthreads();
    #pragma unroll
    for (int d4 = 0; d4 < 64; d4 += 4) {
      float4 xa = *(const float4*)&sX[rp*2+0][d4];
      float4 xb = *(const float4*)&sX[rp*2+1][d4];
      #pragma unroll
      for (int i = 0; i < 8; i++) {
        float4 w = *(const float4*)&sW[kg + 16*i][d4];
        acc[0][i] += xa.x*w.x + xa.y*w.y + xa.z*w.z + xa.w*w.w;
        acc[1][i] += xb.x*w.x + xb.y*w.y + xb.z*w.z + xb.w*w.w;
      }
    }
    __syncthreads();
  }
  #pragma unroll
  for (int r = 0; r < 2; r++) {
    float ss = 0.f;
    #pragma unroll
    for (int i = 0; i < 8; i++) {
      acc[r][i] += bias[kg + 16*i];
      ss += acc[r][i] * acc[r][i];
    }
    ss += __shfl_xor(ss, 1); ss += __shfl_xor(ss, 2);
    ss += __shfl_xor(ss, 4); ss += __shfl_xor(ss, 8);
    float inv = 1.f / fmaxf(sqrtf(ss), 1e-12f);
    int rg = row0 + rp*2 + r;
    if (rg < nRows) {
      #pragma unroll
      for (int i = 0; i < 8; i++) {
        float y = acc[r][i] * inv;
        unsigned short h = f2bf(y);
        unsigned short l = f2bf(y - bf2f(h));
        Yh[(long)rg*K_ + kg + 16*i] = h;
        Yl[(long)rg*K_ + kg + 16*i] = l;
      }
    }
  }
}

// ===== MFMA scores: S[b,q,j] = TEMP * sum_e Q[q,b,e]*K[j,b,e] (hi/lo bf16) =====
__global__ __launch_bounds__(256) void k_scores_mfma(
    const unsigned short* __restrict__ Qh, const unsigned short* __restrict__ Ql,
    const unsigned short* __restrict__ Kh, const unsigned short* __restrict__ Kl,
    float* __restrict__ S, int Lq, int Lk) {
  __shared__ __align__(16) unsigned short sQh[128][40], sQl[128][40];
  __shared__ __align__(16) unsigned short sKh[64][40],  sKl[64][40];
  const int b = blockIdx.z;
  const int q0 = blockIdx.x * 128, j0 = blockIdx.y * 64;
  const int tid = threadIdx.x, wid = tid >> 6, lane = tid & 63;
  floatx4 acc[2][4];
  #pragma unroll
  for (int i = 0; i < 2; i++)
    #pragma unroll
    for (int j = 0; j < 4; j++)
      acc[i][j] = (floatx4){0.f, 0.f, 0.f, 0.f};

  const int qr = tid >> 1, qh16 = (tid & 1) * 16;   // Q stage: 128 rows x 16e
  const int kr = tid >> 2, kq8 = (tid & 3) * 8;     // K stage: 64 rows x 8e

  for (int e0 = 0; e0 < K_; e0 += 32) {
    {
      int qg = q0 + qr;
      if (qg < Lq) {
        const unsigned short* ph = &Qh[((long)qg*B_ + b)*K_ + e0 + qh16];
        const unsigned short* pl = &Ql[((long)qg*B_ + b)*K_ + e0 + qh16];
        *(uint4*)&sQh[qr][qh16]     = *(const uint4*)ph;
        *(uint4*)&sQh[qr][qh16 + 8] = *(const uint4*)(ph + 8);
        *(uint4*)&sQl[qr][qh16]     = *(const uint4*)pl;
        *(uint4*)&sQl[qr][qh16 + 8] = *(const uint4*)(pl + 8);
      } else {
        uint4 z = make_uint4(0,0,0,0);
        *(uint4*)&sQh[qr][qh16] = z; *(uint4*)&sQh[qr][qh16 + 8] = z;
        *(uint4*)&sQl[qr][qh16] = z; *(uint4*)&sQl[qr][qh16 + 8] = z;
      }
    }
    {
      int jg = j0 + kr;
      if (jg < Lk) {
        *(uint4*)&sKh[kr][kq8] = *(const uint4*)&Kh[((long)jg*B_ + b)*K_ + e0 + kq8];
        *(uint4*)&sKl[kr][kq8] = *(const uint4*)&Kl[((long)jg*B_ + b)*K_ + e0 + kq8];
      } else {
        uint4 z = make_uint4(0,0,0,0);
        *(uint4*)&sKh[kr][kq8] = z; *(uint4*)&sKl[kr][kq8] = z;
      }
    }
    __syncthreads();
    {
      const int arow = lane & 15;
      const int kof = (lane >> 4) * 8;
      short8v ah0 = *(const short8v*)&sQh[32*wid + arow][kof];
      short8v ah1 = *(const short8v*)&sQh[32*wid + 16 + arow][kof];
      short8v al0 = *(const short8v*)&sQl[32*wid + arow][kof];
      short8v al1 = *(const short8v*)&sQl[32*wid + 16 + arow][kof];
      #pragma unroll
      for (int td = 0; td < 4; ++td) {
        short8v bh = *(const short8v*)&sKh[16*td + arow][kof];
        short8v bl = *(const short8v*)&sKl[16*td + arow][kof];
        acc[0][td] = __builtin_amdgcn_mfma_f32_16x16x32_bf16(ah0, bh, acc[0][td], 0, 0, 0);
        acc[0][td] = __builtin_amdgcn_mfma_f32_16x16x32_bf16(ah0, bl, acc[0][td], 0, 0, 0);
        acc[0][td] = __builtin_amdgcn_mfma_f32_16x16x32_bf16(al0, bh, acc[0][td], 0, 0, 0);
        acc[1][td] = __builtin_amdgcn_mfma_f32_16x16x32_bf16(ah1, bh, acc[1][td], 0, 0, 0);
        acc[1][td] = __builtin_amdgcn_mfma_f32_16x16x32_bf16(ah1, bl, acc[1][td], 0, 0, 0);
        acc[1][td] = __builtin_amdgcn_mfma_f32_16x16x32_bf16(al1, bh, acc[1][td], 0, 0, 0);
      }
    }
    __syncthreads();
  }
  const int col = lane & 15, row4 = (lane >> 4) * 4;
  #pragma unroll
  for (int tq = 0; tq < 2; ++tq) {
    #pragma unroll
    for (int r = 0; r < 4; ++r) {
      int q = q0 + 32*wid + 16*tq + row4 + r;
      if (q >= Lq) continue;
      float* row = S + ((long)b*Lq + q)*Lk;
      #pragma unroll
      for (int td = 0; td < 4; ++td) {
        int j = j0 + 16*td + col;
        if (j < Lk) row[j] = TEMP_ * acc[tq][td][r];
      }
    }
  }
}

// ------- row softmax: read fp32 in place, WRITE bf16 into row start -------
// bf16 output row: ushort* at same base, len ushorts (first half of fp32 row).
__global__ __launch_bounds__(256) void k_softmax(float* __restrict__ S, int len) {
  __shared__ __align__(16) float buf[1456];
  const long row = blockIdx.x;
  float* p = S + row * (long)len;
  const int tid = threadIdx.x;
  float mx = -1e30f;
  for (int i = tid*4; i < len; i += 1024) {
    float4 v = *(const float4*)&p[i];
    *(float4*)&buf[i] = v;
    mx = fmaxf(mx, fmaxf(fmaxf(v.x, v.y), fmaxf(v.z, v.w)));
  }
  mx = blockReduceMax256(mx);
  float sum = 0.f;
  for (int i = tid*4; i < len; i += 1024) {
    float4 v = *(float4*)&buf[i];
    v.x = __expf(v.x - mx); v.y = __expf(v.y - mx);
    v.z = __expf(v.z - mx); v.w = __expf(v.w - mx);
    sum += v.x + v.y + v.z + v.w;
    *(float4*)&buf[i] = v;
  }
  sum = blockReduceSum256(sum);
  float inv = 1.f / sum;
  unsigned short* po = (unsigned short*)p;
  for (int i = tid*4; i < len; i += 1024) {
    float4 v = *(float4*)&buf[i];
    ushort4 w;
    w.x = f2bf(v.x * inv); w.y = f2bf(v.y * inv);
    w.z = f2bf(v.z * inv); w.w = f2bf(v.w * inv);
    *(ushort4*)&po[i] = w;
  }
}

// ========== MFMA AV: dst[q,b,d] = sum_k S[b,q,k]*(pos1_k)*V[k,b,d] (+R) ==========
// S is bf16 with row stride 2*Lk ushorts (in-place softmax output).
template<bool SCALE>
__global__ __launch_bounds__(256) void k_av_mfma(
    const unsigned short* __restrict__ S, const unsigned short* __restrict__ VT,
    const float* __restrict__ R, const float* __restrict__ label,
    float* __restrict__ dst, int Lq, int Lk, int Mp) {
  __shared__ __align__(16) unsigned short sS[128][40];   // 32 bf16 + pad (80 B rows)
  __shared__ __align__(16) unsigned short sV[64][40];
  const int b = blockIdx.z;
  const int q0 = blockIdx.x * 128, d0 = blockIdx.y * 64;
  const int tid = threadIdx.x;
  const int wid = tid >> 6, lane = tid & 63;
  floatx4 acc[2][4];
  #pragma unroll
  for (int i = 0; i < 2; i++)
    #pragma unroll
    for (int j = 0; j < 4; j++)
      acc[i][j] = (floatx4){0.f, 0.f, 0.f, 0.f};

  const int srr = tid >> 1, shalf = tid & 1;   // S stage: row, 16-col half
  const int vdr = tid >> 2, vq = tid & 3;      // V stage: row, 16B quarter
  const int nch = (Lk + 31) / 32;
  const long sstr = 2L * Lk;                   // ushort stride between S rows

  for (int c = 0; c < nch; ++c) {
    const int k0 = c * 32;
    // --- stage S tile [128 q][32 k] bf16 (optional pos1 scale) ---
    {
      int qg = q0 + srr;
      const int kb = k0 + 16*shalf;
      unsigned short tv[16];
      if (qg < Lq && kb + 16 <= Lk) {
        const unsigned short* sp = &S[(long)(b*Lq + qg)*sstr + kb];
        *(uint4*)&tv[0] = *(const uint4*)sp;
        *(uint4*)&tv[8] = *(const uint4*)(sp + 8);
      } else {
        const unsigned short* sp = &S[(long)(b*Lq + qg)*sstr];
        #pragma unroll
        for (int e = 0; e < 16; ++e) {
          int kk = kb + e;
          tv[e] = (qg < Lq && kk < Lk) ? sp[kk] : (unsigned short)0;
        }
      }
      if (SCALE) {
        #pragma unroll
        for (int e = 0; e < 16; ++e) {
          int kj = kb + e;
          float f = 0.f;
          if (kj < Lk) {
            int pp = kj / HW_, hh = kj - pp*HW_;
            f = bf2f(tv[e]) * label[(pp*B_ + b)*HW_ + hh];
          }
          tv[e] = f2bf(f);
        }
      }
      *(uint4*)&sS[srr][16*shalf]     = *(uint4*)&tv[0];
      *(uint4*)&sS[srr][16*shalf + 8] = *(uint4*)&tv[8];
    }
    // --- stage V tile [64 d][32 k] bf16 from global VT (k-padded, in-bounds) ---
    {
      uint4 v = *(const uint4*)&VT[((long)b*D_ + d0 + vdr)*Mp + k0 + 8*vq];
      *(uint4*)&sV[vdr][8*vq] = v;
    }
    __syncthreads();
    {
      const int arow = lane & 15;
      const int kof = (lane >> 4) * 8;
      short8v a0 = *(const short8v*)&sS[32*wid + arow][kof];
      short8v a1 = *(const short8v*)&sS[32*wid + 16 + arow][kof];
      #pragma unroll
      for (int td = 0; td < 4; ++td) {
        short8v bf = *(const short8v*)&sV[16*td + arow][kof];
        acc[0][td] = __builtin_amdgcn_mfma_f32_16x16x32_bf16(a0, bf, acc[0][td], 0, 0, 0);
        acc[1][td] = __builtin_amdgcn_mfma_f32_16x16x32_bf16(a1, bf, acc[1][td], 0, 0, 0);
      }
    }
    __syncthreads();
  }
  const int col = lane & 15, row4 = (lane >> 4) * 4;
  #pragma unroll
  for (int tq = 0; tq < 2; ++tq) {
    #pragma unroll
    for (int r = 0; r < 4; ++r) {
      int q = q0 + 32*wid + 16*tq + row4 + r;
      if (q >= Lq) continue;
      long base = ((long)q*B_ + b)*D_ + d0 + col;
      #pragma unroll
      for (int td = 0; td < 4; ++td) {
        float v = acc[tq][td][r];
        long idx = base + 16*td;
        if (R) v += R[idx];
        dst[idx] = v;
      }
    }
  }
}

// ------- fused: W2 = per-k label fold of bf16 aff; mask = row-sum -------
// SC bf16 rows stride 2*M_; W2 written bf16 rows stride 2*HW_.
__global__ __launch_bounds__(256) void k_w2m(
    const unsigned short* __restrict__ SC, const float* __restrict__ label,
    unsigned short* __restrict__ W2, float* __restrict__ maskB) {
  const int row = blockIdx.x;            // b*HW_+q
  const int b = row / HW_;
  const int q = row - b*HW_;
  const unsigned short* srow = SC + (long)row * 2 * M_;
  float s = 0.f;
  for (int k = threadIdx.x; k < HW_; k += 256) {
    float w = bf2f(srow[k])         * label[(0*B_ + b)*HW_ + k]
            + bf2f(srow[HW_ + k])   * label[(1*B_ + b)*HW_ + k]
            + bf2f(srow[2*HW_ + k]) * label[(2*B_ + b)*HW_ + k];
    W2[(long)row*2*HW_ + k] = f2bf(w);
    s += w;
  }
  s = blockReduceSum256(s);
  if (threadIdx.x == 0) maskB[q*B_ + b] = s;
}

// ------- inorm pass 1: partial sums of squares per (g,b), 16 chunks -------
template<bool WM>
__global__ __launch_bounds__(256) void k_ss_partial(
    const float* __restrict__ X, const float* __restrict__ X2,
    const float* __restrict__ maskB, float* __restrict__ part) {
  const int gb = blockIdx.x;           // g*B_+b
  const int c = blockIdx.y;            // 0..15
  const int g = gb / B_, b = gb % B_;
  const float4* Xp = (const float4*)X;
  const float4* X2p = (const float4*)X2;
  const int CH = (HW_*D_/4) / 16;
  float s = 0.f;
  for (int i = c*CH + threadIdx.x; i < (c+1)*CH; i += 256) {
    int hw = i >> 7;
    int d4 = i & 127;
    long idx = (((long)g*HW_ + hw)*B_ + b)*(D_/4) + d4;
    float4 v = Xp[idx];
    if (X2p) {
      float4 v2 = X2p[idx];
      v.x += v2.x; v.y += v2.y; v.z += v2.z; v.w += v2.w;
    }
    float m = 1.f;
    if (WM) m = maskB[hw*B_ + b];
    float a = v.x*m, e = v.y*m, f = v.z*m, h = v.w*m;
    s += a*a + e*e + f*f + h*h;
  }
  s = blockReduceSum256(s);
  if (threadIdx.x == 0) part[gb*16 + c] = s;
}

// ------- inorm pass 2: scale factor per group -------
__global__ void k_ss_final(const float* __restrict__ part,
                           float* __restrict__ scaleG, int nG) {
  int g = threadIdx.x;
  if (g < nG) {
    float s = 0.f;
    #pragma unroll
    for (int c = 0; c < 16; c++) s += part[g*16 + c];
    scaleG[g] = NORM_SCALE_ * sqrtf((float)(D_*HW_) / (s + EPS_));
  }
}

// ------- x *= scaleG[g*B+b], x is [G*HW, B, D] viewed as float4 -------
__global__ __launch_bounds__(256) void k_inorm_apply(
    float* __restrict__ X, const float* __restrict__ scaleG, long n4) {
  long i = (long)blockIdx.x*256 + threadIdx.x;
  if (i >= n4) return;
  long t = i >> 7;
  int b = (int)(t & 15);
  long l = t >> 4;
  int g = (int)(l / HW_);
  float sc = scaleG[g*B_ + b];
  float4* Xp = (float4*)X;
  float4 v = Xp[i];
  v.x *= sc; v.y *= sc; v.z *= sc; v.w *= sc;
  Xp[i] = v;
}

// ------- outImg (+)= wts[widx]*scale[b]*((X (+X2)) or tgt*mask) -------
template<int MODE>   // 0: overwrite with tgt*mask ; 1: add (X + X2)
__global__ __launch_bounds__(256) void k_accum(
    const float* __restrict__ X, const float* __restrict__ X2,
    const float* __restrict__ maskB, const float* __restrict__ scaleG,
    const float* __restrict__ wts, float* __restrict__ outI, int widx) {
  long i = (long)blockIdx.x*256 + threadIdx.x;
  const long n4 = (long)HW_*B_*D_/4;
  if (i >= n4) return;
  long t = i >> 7;
  int b = (int)(t & 15);
  int hw = (int)(t >> 4);
  float w = wts[widx] * scaleG[b];
  if (MODE == 0) w *= maskB[hw*B_ + b];
  float4 v = ((const float4*)X)[i];
  if (MODE == 1 && X2) {
    float4 v2 = ((const float4*)X2)[i];
    v.x += v2.x; v.y += v2.y; v.z += v2.z; v.w += v2.w;
  }
  float4* Op = (float4*)outI;
  if (MODE == 0) {
    Op[i] = make_float4(v.x*w, v.y*w, v.z*w, v.w*w);
  } else {
    float4 o = Op[i];
    o.x += v.x*w; o.y += v.y*w; o.z += v.z*w; o.w += v.w*w;
    Op[i] = o;
  }
}

// =======================================================================
extern "C" void kernel_launch(void* const* d_in, const int* in_sizes, int n_in,
                              void* d_out, int out_size, void* d_ws, size_t ws_size,
                              hipStream_t stream) {
  (void)in_sizes; (void)n_in; (void)out_size; (void)ws_size;
  const float* train_feat = (const float*)d_in[0];
  const float* test_feat  = (const float*)d_in[1];
  const float* label      = (const float*)d_in[2];
  const float* sw  = (const float*)d_in[3];
  const float* sb  = (const float*)d_in[4];
  const float* cw  = (const float*)d_in[5];
  const float* cb  = (const float*)d_in[6];
  const float* qxm = (const float*)d_in[7];
  float* out = (float*)d_out;

  // ---- workspace layout (floats); ~343 MB total (unchanged) ----
  float* ws = (float*)d_ws;
  long o = 0;
  float* srcT  = ws + o; o += (long)M_*B_*D_;
  float* tstT  = ws + o; o += (long)M_*B_*D_;
  float* mem   = ws + o; o += (long)M_*B_*D_;
  unsigned short* wqh = (unsigned short*)(ws + o); o += (long)M_*B_*K_/2;
  unsigned short* wql = (unsigned short*)(ws + o); o += (long)M_*B_*K_/2;
  unsigned short* wkh = (unsigned short*)(ws + o); o += (long)M_*B_*K_/2;
  unsigned short* wkl = (unsigned short*)(ws + o); o += (long)M_*B_*K_/2;
  float* big   = ws + o; o += (long)B_*M_*M_;
  float* maskB = ws + o; o += HW_*B_;
  float* part  = ws + o; o += T_*B_*16;
  float* scaleG= ws + o; o += 64;
  float* wts   = ws + o; o += 4;
  unsigned short* srcTT = (unsigned short*)(ws + o); o += (long)B_*D_*MP_M/2;  // reused as memTT
  unsigned short* imTT  = (unsigned short*)(ws + o); o += (long)B_*D_*MP_HW/2;
  unsigned short* tgtTT = (unsigned short*)(ws + o); o += (long)B_*D_*MP_HW/2;
  unsigned short* memTT = srcTT;   // srcTT dead after encoder AV

  // decoder sub-buffers inside `big`
  float* scoresC = big;                               // [B,HW,M] fp32 -> bf16 in place
  float* scoresS = scoresC + (long)B_*HW_*M_;         // [B,HW,HW] fp32 -> bf16 in place
  float* W2f     = scoresS + (long)B_*HW_*HW_;        // [B,HW,HW] region (bf16 used)
  float* tgt     = W2f     + (long)B_*HW_*HW_;        // [HW,B,D]
  float* Xbuf    = tgt     + (long)HW_*B_*D_;         // [HW,B,D]
  float* outImg  = Xbuf    + (long)HW_*B_*D_;         // [HW,B,D]
  unsigned short* W2us = (unsigned short*)W2f;

  const long imgN4 = (long)HW_*B_*D_/4;
  const int  imgBlocks = (int)((imgN4 + 255)/256);

  // ---- input transposes + qxm softmax ----
  k_transpose_in<<<dim3(16,16,T_*B_),256,0,stream>>>(train_feat, srcT);
  k_transpose_in<<<dim3(16,16,T_*B_),256,0,stream>>>(test_feat,  tstT);
  k_wts<<<1,64,0,stream>>>(qxm, wts);

  // ---- encoder: memory = inorm(src + selfattn(src), T) ----
  k_proj_l2n<<<(M_*B_+31)/32,256,0,stream>>>(srcT, sw, sb, wqh, wql, M_*B_);
  k_scores_mfma<<<dim3((M_+127)/128,(M_+63)/64,B_),256,0,stream>>>(
      wqh, wql, wqh, wql, big, M_, M_);
  k_softmax<<<B_*M_,256,0,stream>>>(big, M_);
  k_cvtT<<<dim3(MP_M/32, D_/32, B_),256,0,stream>>>(srcT, srcTT, M_, MP_M);
  k_av_mfma<false><<<dim3((M_+127)/128, D_/64, B_),256,0,stream>>>(
      (const unsigned short*)big, srcTT, srcT, nullptr, mem, M_, M_, MP_M);
  k_ss_partial<false><<<dim3(T_*B_,16),256,0,stream>>>(mem, nullptr, nullptr, part);
  k_ss_final<<<1,64,0,stream>>>(part, scaleG, T_*B_);
  k_inorm_apply<<<(int)(((long)M_*B_*D_/4 + 255)/256),256,0,stream>>>(
      mem, scaleG, (long)M_*B_*D_/4);
  k_cvtT<<<dim3(MP_M/32, D_/32, B_),256,0,stream>>>(mem, memTT, M_, MP_M);
  k_proj_l2n<<<(M_*B_+31)/32,256,0,stream>>>(mem, cw, cb, wkh, wkl, M_*B_);

  // ---- decoder: 3 train images then 3 test images ----
  for (int img = 0; img < 2*T_; img++) {
    const float* base = (img < T_) ? srcT + (long)img*HW_*B_*D_
                                   : tstT + (long)(img - T_)*HW_*B_*D_;
    float* outP = out + (long)img*B_*D_*HW_;

    // self-attention + inorm -> tgt
    k_proj_l2n<<<(HW_*B_+31)/32,256,0,stream>>>(base, sw, sb, wqh, wql, HW_*B_);
    k_cvtT<<<dim3(MP_HW/32, D_/32, B_),256,0,stream>>>(base, imTT, HW_, MP_HW);
    k_scores_mfma<<<dim3((HW_+127)/128,(HW_+63)/64,B_),256,0,stream>>>(
        wqh, wql, wqh, wql, scoresS, HW_, HW_);
    k_softmax<<<B_*HW_,256,0,stream>>>(scoresS, HW_);
    k_av_mfma<false><<<dim3((HW_+127)/128, D_/64, B_),256,0,stream>>>(
        (const unsigned short*)scoresS, imTT, base, nullptr, tgt, HW_, HW_, MP_HW);
    k_ss_partial<false><<<dim3(B_,16),256,0,stream>>>(tgt, nullptr, nullptr, part);
    k_ss_final<<<1,64,0,stream>>>(part, scaleG, B_);
    k_inorm_apply<<<imgBlocks,256,0,stream>>>(tgt, scaleG, imgN4);
    k_cvtT<<<dim3(MP_HW/32, D_/32, B_),256,0,stream>>>(tgt, tgtTT, HW_, MP_HW);

    // shared cross-attention weights aff = softmax(30*wq(tgt)·wk(memory))
    k_proj_l2n<<<(HW_*B_+31)/32,256,0,stream>>>(tgt, cw, cb, wqh, wql, HW_*B_);
    k_scores_mfma<<<dim3((HW_+127)/128,(M_+63)/64,B_),256,0,stream>>>(
        wqh, wql, wkh, wkl, scoresC, HW_, M_);
    k_softmax<<<B_*HW_,256,0,stream>>>(scoresC, M_);

    // W2 (bf16) + mask (fused)
    k_w2m<<<B_*HW_,256,0,stream>>>(
        (const unsigned short*)scoresC, label, W2us, maskB);

    // t_base = inorm(tgt*mask):  out = w0*scale*tgt*mask
    k_ss_partial<true><<<dim3(B_,16),256,0,stream>>>(tgt, nullptr, maskB, part);
    k_ss_final<<<1,64,0,stream>>>(part, scaleG, B_);
    k_accum<0><<<imgBlocks,256,0,stream>>>(
        tgt, nullptr, maskB, scaleG, wts, outImg, 0);

    // t_q = inorm(W2@tgt + tgt):  out += w1*scale*X
    k_av_mfma<false><<<dim3((HW_+127)/128, D_/64, B_),256,0,stream>>>(
        W2us, tgtTT, tgt, nullptr, Xbuf, HW_, HW_, MP_HW);
    k_ss_partial<false><<<dim3(B_,16),256,0,stream>>>(Xbuf, nullptr, nullptr, part);
    k_ss_final<<<1,64,0,stream>>>(part, scaleG, B_);
    k_accum<1><<<imgBlocks,256,0,stream>>>(
        Xbuf, nullptr, nullptr, scaleG, wts, outImg, 1);

    // t_v = inorm((aff*pos1)@memory + tgt):  out += w2*scale*X
    k_av_mfma<true><<<dim3((HW_+127)/128, D_/64, B_),256,0,stream>>>(
        (const unsigned short*)scoresC, memTT, tgt, label, Xbuf, HW_, M_, MP_M);
    k_ss_partial<false><<<dim3(B_,16),256,0,stream>>>(Xbuf, nullptr, nullptr, part);
    k_ss_final<<<1,64,0,stream>>>(part, scaleG, B_);
    k_accum<1><<<imgBlocks,256,0,stream>>>(
        Xbuf, nullptr, nullptr, scaleG, wts, outImg, 2);

    k_out_store<<<dim3(16,16,B_),256,0,stream>>>(outImg, outP);
  }
}